// Round 1
// baseline (1818.328 us; speedup 1.0000x reference)
//
#include <hip/hip_runtime.h>
#include <math.h>

// Problem: B=32, S=512, F=512, T=1024, all fp32.
// Outputs (concat): attn [B,S,1] (16384), a_q [B,1,T] (32768), C [B,T,T] (33554432).
// Workspace layout: ws0 = 64MB (aux, then reused for aux2), logits = B*T floats after it.
// Requires ws_size >= 64MB + 128KB.

#define BM 64
#define BN 64
#define BK 16
#define PAD 4   // LDS row stride = 68 floats (16B aligned, odd*4 -> conflict-light)

__device__ __forceinline__ float fast_tanh(float x) {
    // tanh(x) = 1 - 2/(e^{2x}+1); exp overflow -> inf -> 1, underflow -> 0 -> -1. No NaN.
    return 1.0f - 2.0f / (__expf(2.0f * x) + 1.0f);
}

// D[b] = A @ Bm[b] : A is [M][K] weight (row-major), Bm is [batch][K][N], D is [batch][M][N]
__global__ __launch_bounds__(256)
void gemm_nn(const float* __restrict__ A, const float* __restrict__ Bm,
             float* __restrict__ D, int M, int N, int K) {
    __shared__ float As[BK][BM + PAD];
    __shared__ float Bs[BK][BN + PAD];
    const int b  = blockIdx.z;
    const int m0 = blockIdx.y * BM;
    const int n0 = blockIdx.x * BN;
    const int tx = threadIdx.x, ty = threadIdx.y;
    const int f  = ty * 16 + tx;
    const float* Bb = Bm + (size_t)b * K * N;
    float acc[4][4] = {};
    const int ka = f % 16, ma = f / 16;   // A: 16 rows/pass, 4 passes
    const int nb = f % 64, kb = f / 64;   // B: 4 k-rows/pass, 4 passes
    for (int k0 = 0; k0 < K; k0 += BK) {
        #pragma unroll
        for (int i = 0; i < 4; ++i)
            As[ka][ma + 16 * i] = A[(size_t)(m0 + ma + 16 * i) * K + k0 + ka];
        #pragma unroll
        for (int i = 0; i < 4; ++i)
            Bs[kb + 4 * i][nb] = Bb[(size_t)(k0 + kb + 4 * i) * N + n0 + nb];
        __syncthreads();
        #pragma unroll
        for (int k = 0; k < BK; ++k) {
            float av[4], bv[4];
            *(float4*)av = *(const float4*)&As[k][ty * 4];
            *(float4*)bv = *(const float4*)&Bs[k][tx * 4];
            #pragma unroll
            for (int i = 0; i < 4; ++i)
                #pragma unroll
                for (int j = 0; j < 4; ++j)
                    acc[i][j] += av[i] * bv[j];
        }
        __syncthreads();
    }
    float* Db = D + (size_t)b * M * N;
    #pragma unroll
    for (int i = 0; i < 4; ++i) {
        float4 v = make_float4(acc[i][0], acc[i][1], acc[i][2], acc[i][3]);
        *(float4*)&Db[(size_t)(m0 + ty * 4 + i) * N + n0 + tx * 4] = v;
    }
}

// C[b][m][n] = tanh( sum_k ZR[b][k][m] * AUX[b][k][n] )  (TN GEMM, K-major operands)
__global__ __launch_bounds__(256)
void gemm_tn_tanh(const float* __restrict__ ZR, const float* __restrict__ AUX,
                  float* __restrict__ C, int M, int N, int K) {
    __shared__ float As[BK][BM + PAD];
    __shared__ float Bs[BK][BN + PAD];
    const int b  = blockIdx.z;
    const int m0 = blockIdx.y * BM;
    const int n0 = blockIdx.x * BN;
    const int tx = threadIdx.x, ty = threadIdx.y;
    const int f  = ty * 16 + tx;
    const float* ZRb  = ZR  + (size_t)b * K * M;
    const float* AUXb = AUX + (size_t)b * K * N;
    float acc[4][4] = {};
    const int nl = f % 64, kl = f / 64;   // both operands: fast dim contiguous
    for (int k0 = 0; k0 < K; k0 += BK) {
        #pragma unroll
        for (int i = 0; i < 4; ++i)
            As[kl + 4 * i][nl] = ZRb[(size_t)(k0 + kl + 4 * i) * M + m0 + nl];
        #pragma unroll
        for (int i = 0; i < 4; ++i)
            Bs[kl + 4 * i][nl] = AUXb[(size_t)(k0 + kl + 4 * i) * N + n0 + nl];
        __syncthreads();
        #pragma unroll
        for (int k = 0; k < BK; ++k) {
            float av[4], bv[4];
            *(float4*)av = *(const float4*)&As[k][ty * 4];
            *(float4*)bv = *(const float4*)&Bs[k][tx * 4];
            #pragma unroll
            for (int i = 0; i < 4; ++i)
                #pragma unroll
                for (int j = 0; j < 4; ++j)
                    acc[i][j] += av[i] * bv[j];
        }
        __syncthreads();
    }
    float* Cb = C + (size_t)b * M * N;
    #pragma unroll
    for (int i = 0; i < 4; ++i) {
        float4 v = make_float4(fast_tanh(acc[i][0]), fast_tanh(acc[i][1]),
                               fast_tanh(acc[i][2]), fast_tanh(acc[i][3]));
        *(float4*)&Cb[(size_t)(m0 + ty * 4 + i) * N + n0 + tx * 4] = v;
    }
}

// Fused: per (f,t) tile
//   acc3 = (W_q @ z_robot[b]) tile        (K1 = S, computed on the fly — aux3 never hits HBM)
//   acc  = (aux2[b] @ C[b]^T) tile        (K2 = T, NT: both K-contiguous)
//   logits[b][t] += sum_f w_hq[f] * tanh(acc3 + acc)   (H_q never materialized)
__global__ __launch_bounds__(256)
void gemm_nt_fused(const float* __restrict__ Wq,  // [M][K1]
                   const float* __restrict__ ZR,  // [batch][K1][N]
                   const float* __restrict__ A2,  // [batch][M][K2]
                   const float* __restrict__ Cm,  // [batch][N][K2]
                   const float* __restrict__ whq, // [M]
                   float* __restrict__ logits,    // [batch][N]
                   int M, int N, int K1, int K2) {
    __shared__ float As[BK][BM + PAD];
    __shared__ float Bs[BK][BN + PAD];
    __shared__ float red[16][BN];
    const int b  = blockIdx.z;
    const int m0 = blockIdx.y * BM;
    const int n0 = blockIdx.x * BN;
    const int tx = threadIdx.x, ty = threadIdx.y;
    const int f  = ty * 16 + tx;
    const float* ZRb = ZR + (size_t)b * K1 * N;
    const float* A2b = A2 + (size_t)b * M * K2;
    const float* Cb  = Cm + (size_t)b * N * K2;

    // ---- Phase A: acc3 = W_q @ z_robot tile (A is K-contiguous rows; B is K-major) ----
    float acc3[4][4] = {};
    {
        const int ka = f % 16, ma = f / 16;
        const int nb = f % 64, kb = f / 64;
        for (int k0 = 0; k0 < K1; k0 += BK) {
            #pragma unroll
            for (int i = 0; i < 4; ++i)
                As[ka][ma + 16 * i] = Wq[(size_t)(m0 + ma + 16 * i) * K1 + k0 + ka];
            #pragma unroll
            for (int i = 0; i < 4; ++i)
                Bs[kb + 4 * i][nb] = ZRb[(size_t)(k0 + kb + 4 * i) * N + n0 + nb];
            __syncthreads();
            #pragma unroll
            for (int k = 0; k < BK; ++k) {
                float av[4], bv[4];
                *(float4*)av = *(const float4*)&As[k][ty * 4];
                *(float4*)bv = *(const float4*)&Bs[k][tx * 4];
                #pragma unroll
                for (int i = 0; i < 4; ++i)
                    #pragma unroll
                    for (int j = 0; j < 4; ++j)
                        acc3[i][j] += av[i] * bv[j];
            }
            __syncthreads();
        }
    }

    // ---- Phase B: acc = aux2 @ C^T tile (NT: both rows K-contiguous) ----
    float acc[4][4] = {};
    {
        const int ka = f % 16, ra = f / 16;
        for (int k0 = 0; k0 < K2; k0 += BK) {
            #pragma unroll
            for (int i = 0; i < 4; ++i)
                As[ka][ra + 16 * i] = A2b[(size_t)(m0 + ra + 16 * i) * K2 + k0 + ka];
            #pragma unroll
            for (int i = 0; i < 4; ++i)
                Bs[ka][ra + 16 * i] = Cb[(size_t)(n0 + ra + 16 * i) * K2 + k0 + ka];
            __syncthreads();
            #pragma unroll
            for (int k = 0; k < BK; ++k) {
                float av[4], bv[4];
                *(float4*)av = *(const float4*)&As[k][ty * 4];
                *(float4*)bv = *(const float4*)&Bs[k][tx * 4];
                #pragma unroll
                for (int i = 0; i < 4; ++i)
                    #pragma unroll
                    for (int j = 0; j < 4; ++j)
                        acc[i][j] += av[i] * bv[j];
            }
            __syncthreads();
        }
    }

    // ---- Epilogue: H = tanh(acc3 + acc); p[t] = sum_f w_hq[f]*H; reduce over block ----
    float p[4] = {0.f, 0.f, 0.f, 0.f};
    #pragma unroll
    for (int i = 0; i < 4; ++i) {
        const float w = whq[m0 + ty * 4 + i];
        #pragma unroll
        for (int j = 0; j < 4; ++j)
            p[j] += w * fast_tanh(acc3[i][j] + acc[i][j]);
    }
    #pragma unroll
    for (int j = 0; j < 4; ++j)
        red[ty][tx * 4 + j] = p[j];
    __syncthreads();
    if (f < BN) {
        float s = 0.f;
        #pragma unroll
        for (int r = 0; r < 16; ++r) s += red[r][f];
        atomicAdd(&logits[(size_t)b * N + n0 + f], s);
    }
}

__global__ __launch_bounds__(256)
void softmax_kernel(const float* __restrict__ logits, float* __restrict__ aq, int T) {
    __shared__ float sm[256];
    const int b = blockIdx.x, tid = threadIdx.x;
    float v[4];
    float mx = -1e30f;
    #pragma unroll
    for (int i = 0; i < 4; ++i) {
        v[i] = logits[(size_t)b * T + tid + 256 * i];
        mx = fmaxf(mx, v[i]);
    }
    sm[tid] = mx; __syncthreads();
    for (int s = 128; s > 0; s >>= 1) {
        if (tid < s) sm[tid] = fmaxf(sm[tid], sm[tid + s]);
        __syncthreads();
    }
    mx = sm[0]; __syncthreads();
    float e[4], sum = 0.f;
    #pragma unroll
    for (int i = 0; i < 4; ++i) { e[i] = __expf(v[i] - mx); sum += e[i]; }
    sm[tid] = sum; __syncthreads();
    for (int s = 128; s > 0; s >>= 1) {
        if (tid < s) sm[tid] += sm[tid + s];
        __syncthreads();
    }
    const float inv = 1.0f / sm[0];
    #pragma unroll
    for (int i = 0; i < 4; ++i)
        aq[(size_t)b * T + tid + 256 * i] = e[i] * inv;
}

// attn[b][s] = sum_t z_robot[b][s][t] * a_q[b][t]   (one wave per s-row)
__global__ __launch_bounds__(256)
void attn_kernel(const float* __restrict__ ZR, const float* __restrict__ aq,
                 float* __restrict__ out, int S, int T) {
    const int b = blockIdx.y;
    const int s = blockIdx.x * 4 + (threadIdx.x >> 6);
    const int lane = threadIdx.x & 63;
    const float* row = ZR + ((size_t)b * S + s) * T;
    const float* a = aq + (size_t)b * T;
    float sum = 0.f;
    for (int t = lane; t < T; t += 64) sum += row[t] * a[t];
    #pragma unroll
    for (int off = 32; off > 0; off >>= 1) sum += __shfl_down(sum, off, 64);
    if (lane == 0) out[(size_t)b * S + s] = sum;
}

extern "C" void kernel_launch(void* const* d_in, const int* in_sizes, int n_in,
                              void* d_out, int out_size, void* d_ws, size_t ws_size,
                              hipStream_t stream) {
    const float* z_robot = (const float*)d_in[0];
    const float* z_human = (const float*)d_in[1];
    const float* W_b     = (const float*)d_in[2];
    const float* W_q     = (const float*)d_in[3];
    const float* W_v     = (const float*)d_in[4];
    const float* w_hq    = (const float*)d_in[5];
    float* out = (float*)d_out;

    const int Bn = 32, S = 512, F = 512, T = 1024;
    float* attn_out = out;                       // B*S
    float* aq_out   = out + (size_t)Bn * S;      // B*T
    float* C_out    = out + (size_t)Bn * S + (size_t)Bn * T;  // B*T*T

    char* ws = (char*)d_ws;
    float* ws0    = (float*)ws;                                   // 64MB: aux then aux2
    float* logits = (float*)(ws + (size_t)Bn * S * T * 4);        // B*T floats

    hipMemsetAsync(logits, 0, (size_t)Bn * T * sizeof(float), stream);

    dim3 blk(16, 16);
    // aux = W_b @ z_human  -> ws0
    gemm_nn<<<dim3(T / BN, S / BM, Bn), blk, 0, stream>>>(W_b, z_human, ws0, S, T, S);
    // C = tanh(z_robot^T @ aux) -> d_out
    gemm_tn_tanh<<<dim3(T / BN, T / BM, Bn), blk, 0, stream>>>(z_robot, ws0, C_out, T, T, S);
    // aux2 = W_v @ z_human -> ws0 (aux is dead now)
    gemm_nn<<<dim3(T / BN, F / BM, Bn), blk, 0, stream>>>(W_v, z_human, ws0, F, T, S);
    // logits via fused (aux3-on-the-fly + aux2@C^T + tanh + w_hq reduction)
    gemm_nt_fused<<<dim3(T / BN, F / BM, Bn), blk, 0, stream>>>(
        W_q, z_robot, ws0, C_out, w_hq, logits, F, T, S, T);
    // a_q = softmax(logits)
    softmax_kernel<<<dim3(Bn), dim3(256), 0, stream>>>(logits, aq_out, T);
    // attn = z_robot @ a_q^T
    attn_kernel<<<dim3(S / 4, Bn), dim3(256), 0, stream>>>(z_robot, aq_out, attn_out, S, T);
}

// Round 2
// 607.279 us; speedup vs baseline: 2.9942x; 2.9942x over previous
//
#include <hip/hip_runtime.h>
#include <math.h>

// Content_Attn: B=32, S=512, F=512, T=1024, fp32 in/out.
// Outputs concat: attn [B,S,1] (16384), a_q [B,1,T] (32768), C [B,T,T] (33.5M).
//
// FAST path (needs ws >= ~271MB): MFMA bf16, split-precision (x3) for aux & C,
// plain bf16 for aux2/aux3/H_q/logits. FALLBACK: round-1 fp32 path (ws >= ~68MB).

using f32x4  = __attribute__((ext_vector_type(4))) float;
using bf16x8 = __attribute__((ext_vector_type(8))) short;

__device__ __forceinline__ ushort f2bf(float x) {
    uint u = __float_as_uint(x);
    return (ushort)((u + 0x7fffu + ((u >> 16) & 1u)) >> 16);  // RNE
}
__device__ __forceinline__ float bf2f(ushort h) { return __uint_as_float((uint)h << 16); }

__device__ __forceinline__ float fast_tanh(float x) {
    // tanh(x) = 1 - 2/(e^{2x}+1); overflow -> 1, underflow -> -1, no NaN.
    return 1.0f - 2.0f / (__expf(2.0f * x) + 1.0f);
}

// async global->LDS, 16B per lane; LDS dst = wave-uniform base + lane*16
__device__ __forceinline__ void gll16(const void* g, void* l) {
    __builtin_amdgcn_global_load_lds(
        (__attribute__((address_space(1))) void*)(void*)g,
        (__attribute__((address_space(3))) void*)l, 16, 0, 0);
}

// ---------------------------------------------------------------------------
// Conversion kernels
// ---------------------------------------------------------------------------

// in fp32 [b][R][Cn] -> hi/lo bf16 [b][Cn][R] (transpose + split)
__global__ __launch_bounds__(256)
void transpose_split_k(const float* __restrict__ in, ushort* __restrict__ hi,
                       ushort* __restrict__ lo, int R, int Cn) {
    __shared__ float tile[32][33];
    const int b = blockIdx.z;
    const float* inb = in + (size_t)b * R * Cn;
    const int c0 = blockIdx.x * 32, r0 = blockIdx.y * 32;
    const int tx = threadIdx.x, ty = threadIdx.y;  // 32 x 8
    #pragma unroll
    for (int i = 0; i < 32; i += 8)
        tile[ty + i][tx] = inb[(size_t)(r0 + ty + i) * Cn + c0 + tx];
    __syncthreads();
    const size_t ob = (size_t)b * R * Cn;
    #pragma unroll
    for (int i = 0; i < 32; i += 8) {
        const float v = tile[tx][ty + i];
        const ushort h = f2bf(v);
        const size_t o = ob + (size_t)(c0 + ty + i) * R + r0 + tx;
        hi[o] = h;
        lo[o] = f2bf(v - bf2f(h));
    }
}

// elementwise fp32 -> bf16 hi (+ optional lo)
__global__ __launch_bounds__(256)
void convert_split_k(const float* __restrict__ in, ushort* __restrict__ hi,
                     ushort* __restrict__ lo, int n) {
    const int i = blockIdx.x * 256 + threadIdx.x;
    if (i < n) {
        const float v = in[i];
        const ushort h = f2bf(v);
        hi[i] = h;
        if (lo) lo[i] = f2bf(v - bf2f(h));
    }
}

// ---------------------------------------------------------------------------
// Split-precision MFMA GEMM (BK=32): D = A*B^T-ish with A[m][k], B[n][k] layouts.
// MODE 0: store result split (hi/lo bf16).  MODE 1: tanh -> fp32 + bf16.
// ---------------------------------------------------------------------------
template <int MODE>
__global__ __launch_bounds__(256)
void gemm_split(const ushort* __restrict__ Ahi, const ushort* __restrict__ Alo,
                long sAb, int ldA,
                const ushort* __restrict__ Bhi, const ushort* __restrict__ Blo,
                long sBb, int ldB, int K,
                ushort* __restrict__ Ohi, ushort* __restrict__ Olo,
                float* __restrict__ Of, ushort* __restrict__ O16,
                int ldO, long sOb) {
    __shared__ __align__(16) ushort lds[16384];  // Ahi|Alo|Bhi|Blo each 128x32
    const int b = blockIdx.z, m0 = blockIdx.y * 128, n0 = blockIdx.x * 128;
    const int t = threadIdx.x, l = t & 63, w = t >> 6, wm = w >> 1, wn = w & 1;

    // staging: per inst 16 rows x 4 chunks(16B); source chunk XOR-swizzled
    const int srow = l >> 2;
    const int sch  = ((l & 3) ^ (srow & 3)) * 8;
    const ushort* pAh = Ahi + (long)b * sAb + (long)(m0 + w * 32 + srow) * ldA + sch;
    const ushort* pAl = Alo + (long)b * sAb + (long)(m0 + w * 32 + srow) * ldA + sch;
    const ushort* pBh = Bhi + (long)b * sBb + (long)(n0 + w * 32 + srow) * ldB + sch;
    const ushort* pBl = Blo + (long)b * sBb + (long)(n0 + w * 32 + srow) * ldB + sch;

    const int q = l >> 4;
    int offA[4], offB[4];
    #pragma unroll
    for (int i = 0; i < 4; ++i) {
        const int rA = wm * 64 + i * 16 + (l & 15);
        offA[i] = rA * 32 + (q ^ (rA & 3)) * 8;
        const int rB = wn * 64 + i * 16 + (l & 15);
        offB[i] = rB * 32 + (q ^ (rB & 3)) * 8;
    }

    f32x4 acc[4][4] = {};
    for (int k0 = 0; k0 < K; k0 += 32) {
        #pragma unroll
        for (int tt = 0; tt < 2; ++tt) {
            const int lo_ = (w * 32 + tt * 16) * 32;
            gll16(pAh + (long)(tt * 16) * ldA + k0, lds + lo_);
            gll16(pAl + (long)(tt * 16) * ldA + k0, lds + 4096 + lo_);
            gll16(pBh + (long)(tt * 16) * ldB + k0, lds + 8192 + lo_);
            gll16(pBl + (long)(tt * 16) * ldB + k0, lds + 12288 + lo_);
        }
        __syncthreads();
        bf16x8 ah[4], al4[4], bh[4], bl4[4];
        #pragma unroll
        for (int i = 0; i < 4; ++i) {
            ah[i]  = *(const bf16x8*)&lds[offA[i]];
            al4[i] = *(const bf16x8*)&lds[4096 + offA[i]];
            bh[i]  = *(const bf16x8*)&lds[8192 + offB[i]];
            bl4[i] = *(const bf16x8*)&lds[12288 + offB[i]];
        }
        #pragma unroll
        for (int i = 0; i < 4; ++i)
            #pragma unroll
            for (int j = 0; j < 4; ++j) {
                acc[i][j] = __builtin_amdgcn_mfma_f32_16x16x32_bf16(ah[i],  bh[j],  acc[i][j], 0, 0, 0);
                acc[i][j] = __builtin_amdgcn_mfma_f32_16x16x32_bf16(ah[i],  bl4[j], acc[i][j], 0, 0, 0);
                acc[i][j] = __builtin_amdgcn_mfma_f32_16x16x32_bf16(al4[i], bh[j],  acc[i][j], 0, 0, 0);
            }
        __syncthreads();
    }

    const int cl = l & 15, rl = (l >> 4) * 4;
    #pragma unroll
    for (int i = 0; i < 4; ++i)
        #pragma unroll
        for (int r = 0; r < 4; ++r) {
            const long mg = m0 + wm * 64 + i * 16 + rl + r;
            #pragma unroll
            for (int j = 0; j < 4; ++j) {
                const int ng = n0 + wn * 64 + j * 16 + cl;
                const float v = acc[i][j][r];
                const long o = (long)b * sOb + mg * ldO + ng;
                if (MODE == 0) {
                    const ushort h = f2bf(v);
                    Ohi[o] = h;
                    Olo[o] = f2bf(v - bf2f(h));
                } else {
                    const float tv = fast_tanh(v);
                    Of[o] = tv;
                    O16[o] = f2bf(tv);
                }
            }
        }
}

// ---------------------------------------------------------------------------
// Plain bf16 MFMA core (BK=64), accumulates into caller's acc.
// ---------------------------------------------------------------------------
__device__ __forceinline__ void plain_core(
    const ushort* __restrict__ A, long sAb, int ldA,
    const ushort* __restrict__ B, long sBb, int ldB, int K,
    int b, int m0, int n0, ushort* lds, f32x4 (&acc)[4][4]) {
    const int t = threadIdx.x, l = t & 63, w = t >> 6, wm = w >> 1, wn = w & 1;
    const int srow = l >> 3;
    const int sch  = ((l & 7) ^ (srow & 7)) * 8;
    const ushort* pA = A + (long)b * sAb + (long)(m0 + w * 32 + srow) * ldA + sch;
    const ushort* pB = B + (long)b * sBb + (long)(n0 + w * 32 + srow) * ldB + sch;
    const int q = l >> 4;
    int offA[4], offB[4];
    #pragma unroll
    for (int i = 0; i < 4; ++i) {
        const int rA = wm * 64 + i * 16 + (l & 15);
        offA[i] = rA * 64 + (q ^ (rA & 7)) * 8;
        const int rB = wn * 64 + i * 16 + (l & 15);
        offB[i] = 8192 + rB * 64 + (q ^ (rB & 7)) * 8;
    }
    for (int k0 = 0; k0 < K; k0 += 64) {
        #pragma unroll
        for (int tt = 0; tt < 4; ++tt) {
            gll16(pA + (long)(tt * 8) * ldA + k0, lds + (w * 32 + tt * 8) * 64);
            gll16(pB + (long)(tt * 8) * ldB + k0, lds + 8192 + (w * 32 + tt * 8) * 64);
        }
        __syncthreads();
        #pragma unroll
        for (int s = 0; s < 2; ++s) {
            bf16x8 av[4], bv[4];
            #pragma unroll
            for (int i = 0; i < 4; ++i) {
                av[i] = *(const bf16x8*)&lds[offA[i] ^ (s * 32)];
                bv[i] = *(const bf16x8*)&lds[offB[i] ^ (s * 32)];
            }
            #pragma unroll
            for (int i = 0; i < 4; ++i)
                #pragma unroll
                for (int j = 0; j < 4; ++j)
                    acc[i][j] = __builtin_amdgcn_mfma_f32_16x16x32_bf16(av[i], bv[j], acc[i][j], 0, 0, 0);
        }
        __syncthreads();
    }
}

// G3: aux2 = Wv @ zh  (store bf16)
__global__ __launch_bounds__(256)
void gemm_plain_store(const ushort* __restrict__ A, long sAb, int ldA,
                      const ushort* __restrict__ B, long sBb, int ldB, int K,
                      ushort* __restrict__ O, long sOb, int ldO) {
    __shared__ __align__(16) ushort lds[16384];
    const int b = blockIdx.z, m0 = blockIdx.y * 128, n0 = blockIdx.x * 128;
    f32x4 acc[4][4] = {};
    plain_core(A, sAb, ldA, B, sBb, ldB, K, b, m0, n0, lds, acc);
    const int t = threadIdx.x, l = t & 63, w = t >> 6, wm = w >> 1, wn = w & 1;
    const int cl = l & 15, rl = (l >> 4) * 4;
    #pragma unroll
    for (int i = 0; i < 4; ++i)
        #pragma unroll
        for (int r = 0; r < 4; ++r) {
            const long mg = m0 + wm * 64 + i * 16 + rl + r;
            #pragma unroll
            for (int j = 0; j < 4; ++j)
                O[(long)b * sOb + mg * ldO + n0 + wn * 64 + j * 16 + cl] = f2bf(acc[i][j][r]);
        }
}

// G4: acc = Wq@zr + aux2@C^T; H=tanh(acc); logits[t] += sum_f whq[f]*H[f][t]
__global__ __launch_bounds__(256)
void gemm_fused_logits(const ushort* __restrict__ Wq16, const ushort* __restrict__ zrT,
                       const ushort* __restrict__ aux2, const ushort* __restrict__ C16,
                       const float* __restrict__ whq, float* __restrict__ logits) {
    __shared__ __align__(16) ushort lds[16384];
    const int b = blockIdx.z, m0 = blockIdx.y * 128, n0 = blockIdx.x * 128;
    f32x4 acc[4][4] = {};
    plain_core(Wq16, 0, 512, zrT, 524288, 512, 512, b, m0, n0, lds, acc);
    plain_core(aux2, 524288, 1024, C16, 1048576, 1024, 1024, b, m0, n0, lds, acc);
    const int t = threadIdx.x, l = t & 63, w = t >> 6, wm = w >> 1, wn = w & 1;
    float p[4] = {0.f, 0.f, 0.f, 0.f};
    #pragma unroll
    for (int i = 0; i < 4; ++i)
        #pragma unroll
        for (int r = 0; r < 4; ++r) {
            const float wv = whq[m0 + wm * 64 + i * 16 + (l >> 4) * 4 + r];
            #pragma unroll
            for (int j = 0; j < 4; ++j)
                p[j] += wv * fast_tanh(acc[i][j][r]);
        }
    #pragma unroll
    for (int j = 0; j < 4; ++j) {
        p[j] += __shfl_xor(p[j], 16);
        p[j] += __shfl_xor(p[j], 32);
    }
    float* red = (float*)lds;  // [2][128], reuse LDS (all reads drained by barrier)
    __syncthreads();
    if (l < 16) {
        #pragma unroll
        for (int j = 0; j < 4; ++j)
            red[wm * 128 + wn * 64 + j * 16 + l] = p[j];
    }
    __syncthreads();
    if (t < 128)
        atomicAdd(&logits[(long)b * 1024 + n0 + t], red[t] + red[128 + t]);
}

// ---------------------------------------------------------------------------
// Softmax + attn tail (shared by both paths)
// ---------------------------------------------------------------------------
__global__ __launch_bounds__(256)
void softmax_kernel(const float* __restrict__ logits, float* __restrict__ aq, int T) {
    __shared__ float sm[256];
    const int b = blockIdx.x, tid = threadIdx.x;
    float v[4];
    float mx = -1e30f;
    #pragma unroll
    for (int i = 0; i < 4; ++i) {
        v[i] = logits[(size_t)b * T + tid + 256 * i];
        mx = fmaxf(mx, v[i]);
    }
    sm[tid] = mx; __syncthreads();
    for (int s = 128; s > 0; s >>= 1) {
        if (tid < s) sm[tid] = fmaxf(sm[tid], sm[tid + s]);
        __syncthreads();
    }
    mx = sm[0]; __syncthreads();
    float e[4], sum = 0.f;
    #pragma unroll
    for (int i = 0; i < 4; ++i) { e[i] = __expf(v[i] - mx); sum += e[i]; }
    sm[tid] = sum; __syncthreads();
    for (int s = 128; s > 0; s >>= 1) {
        if (tid < s) sm[tid] += sm[tid + s];
        __syncthreads();
    }
    const float inv = 1.0f / sm[0];
    #pragma unroll
    for (int i = 0; i < 4; ++i)
        aq[(size_t)b * T + tid + 256 * i] = e[i] * inv;
}

__global__ __launch_bounds__(256)
void attn_kernel(const float* __restrict__ ZR, const float* __restrict__ aq,
                 float* __restrict__ out, int S, int T) {
    const int b = blockIdx.y;
    const int s = blockIdx.x * 4 + (threadIdx.x >> 6);
    const int lane = threadIdx.x & 63;
    const float* row = ZR + ((size_t)b * S + s) * T;
    const float* a = aq + (size_t)b * T;
    float sum = 0.f;
    for (int t = lane; t < T; t += 64) sum += row[t] * a[t];
    #pragma unroll
    for (int off = 32; off > 0; off >>= 1) sum += __shfl_down(sum, off, 64);
    if (lane == 0) out[(size_t)b * S + s] = sum;
}

// ---------------------------------------------------------------------------
// FALLBACK fp32 path (round-1 kernels, proven; needs ~68MB ws)
// ---------------------------------------------------------------------------
#define BM 64
#define BN 64
#define BK 16
#define PAD 4

__global__ __launch_bounds__(256)
void gemm_nn(const float* __restrict__ A, const float* __restrict__ Bm,
             float* __restrict__ D, int M, int N, int K) {
    __shared__ float As[BK][BM + PAD];
    __shared__ float Bs[BK][BN + PAD];
    const int b = blockIdx.z, m0 = blockIdx.y * BM, n0 = blockIdx.x * BN;
    const int tx = threadIdx.x, ty = threadIdx.y, f = ty * 16 + tx;
    const float* Bb = Bm + (size_t)b * K * N;
    float acc[4][4] = {};
    const int ka = f % 16, ma = f / 16, nb = f % 64, kb = f / 64;
    for (int k0 = 0; k0 < K; k0 += BK) {
        #pragma unroll
        for (int i = 0; i < 4; ++i)
            As[ka][ma + 16 * i] = A[(size_t)(m0 + ma + 16 * i) * K + k0 + ka];
        #pragma unroll
        for (int i = 0; i < 4; ++i)
            Bs[kb + 4 * i][nb] = Bb[(size_t)(k0 + kb + 4 * i) * N + n0 + nb];
        __syncthreads();
        #pragma unroll
        for (int k = 0; k < BK; ++k) {
            float av[4], bv[4];
            *(float4*)av = *(const float4*)&As[k][ty * 4];
            *(float4*)bv = *(const float4*)&Bs[k][tx * 4];
            #pragma unroll
            for (int i = 0; i < 4; ++i)
                #pragma unroll
                for (int j = 0; j < 4; ++j) acc[i][j] += av[i] * bv[j];
        }
        __syncthreads();
    }
    float* Db = D + (size_t)b * M * N;
    #pragma unroll
    for (int i = 0; i < 4; ++i)
        *(float4*)&Db[(size_t)(m0 + ty * 4 + i) * N + n0 + tx * 4] =
            make_float4(acc[i][0], acc[i][1], acc[i][2], acc[i][3]);
}

__global__ __launch_bounds__(256)
void gemm_tn_tanh(const float* __restrict__ ZR, const float* __restrict__ AUX,
                  float* __restrict__ C, int M, int N, int K) {
    __shared__ float As[BK][BM + PAD];
    __shared__ float Bs[BK][BN + PAD];
    const int b = blockIdx.z, m0 = blockIdx.y * BM, n0 = blockIdx.x * BN;
    const int tx = threadIdx.x, ty = threadIdx.y, f = ty * 16 + tx;
    const float* ZRb = ZR + (size_t)b * K * M;
    const float* AUXb = AUX + (size_t)b * K * N;
    float acc[4][4] = {};
    const int nl = f % 64, kl = f / 64;
    for (int k0 = 0; k0 < K; k0 += BK) {
        #pragma unroll
        for (int i = 0; i < 4; ++i)
            As[kl + 4 * i][nl] = ZRb[(size_t)(k0 + kl + 4 * i) * M + m0 + nl];
        #pragma unroll
        for (int i = 0; i < 4; ++i)
            Bs[kl + 4 * i][nl] = AUXb[(size_t)(k0 + kl + 4 * i) * N + n0 + nl];
        __syncthreads();
        #pragma unroll
        for (int k = 0; k < BK; ++k) {
            float av[4], bv[4];
            *(float4*)av = *(const float4*)&As[k][ty * 4];
            *(float4*)bv = *(const float4*)&Bs[k][tx * 4];
            #pragma unroll
            for (int i = 0; i < 4; ++i)
                #pragma unroll
                for (int j = 0; j < 4; ++j) acc[i][j] += av[i] * bv[j];
        }
        __syncthreads();
    }
    float* Cb = C + (size_t)b * M * N;
    #pragma unroll
    for (int i = 0; i < 4; ++i)
        *(float4*)&Cb[(size_t)(m0 + ty * 4 + i) * N + n0 + tx * 4] =
            make_float4(fast_tanh(acc[i][0]), fast_tanh(acc[i][1]),
                        fast_tanh(acc[i][2]), fast_tanh(acc[i][3]));
}

__global__ __launch_bounds__(256)
void gemm_nt_fused(const float* __restrict__ Wq, const float* __restrict__ ZR,
                   const float* __restrict__ A2, const float* __restrict__ Cm,
                   const float* __restrict__ whq, float* __restrict__ logits,
                   int M, int N, int K1, int K2) {
    __shared__ float As[BK][BM + PAD];
    __shared__ float Bs[BK][BN + PAD];
    __shared__ float red[16][BN];
    const int b = blockIdx.z, m0 = blockIdx.y * BM, n0 = blockIdx.x * BN;
    const int tx = threadIdx.x, ty = threadIdx.y, f = ty * 16 + tx;
    const float* ZRb = ZR + (size_t)b * K1 * N;
    const float* A2b = A2 + (size_t)b * M * K2;
    const float* Cb = Cm + (size_t)b * N * K2;
    float acc3[4][4] = {};
    {
        const int ka = f % 16, ma = f / 16, nb = f % 64, kb = f / 64;
        for (int k0 = 0; k0 < K1; k0 += BK) {
            #pragma unroll
            for (int i = 0; i < 4; ++i)
                As[ka][ma + 16 * i] = Wq[(size_t)(m0 + ma + 16 * i) * K1 + k0 + ka];
            #pragma unroll
            for (int i = 0; i < 4; ++i)
                Bs[kb + 4 * i][nb] = ZRb[(size_t)(k0 + kb + 4 * i) * N + n0 + nb];
            __syncthreads();
            #pragma unroll
            for (int k = 0; k < BK; ++k) {
                float av[4], bv[4];
                *(float4*)av = *(const float4*)&As[k][ty * 4];
                *(float4*)bv = *(const float4*)&Bs[k][tx * 4];
                #pragma unroll
                for (int i = 0; i < 4; ++i)
                    #pragma unroll
                    for (int j = 0; j < 4; ++j) acc3[i][j] += av[i] * bv[j];
            }
            __syncthreads();
        }
    }
    float acc[4][4] = {};
    {
        const int ka = f % 16, ra = f / 16;
        for (int k0 = 0; k0 < K2; k0 += BK) {
            #pragma unroll
            for (int i = 0; i < 4; ++i)
                As[ka][ra + 16 * i] = A2b[(size_t)(m0 + ra + 16 * i) * K2 + k0 + ka];
            #pragma unroll
            for (int i = 0; i < 4; ++i)
                Bs[ka][ra + 16 * i] = Cb[(size_t)(n0 + ra + 16 * i) * K2 + k0 + ka];
            __syncthreads();
            #pragma unroll
            for (int k = 0; k < BK; ++k) {
                float av[4], bv[4];
                *(float4*)av = *(const float4*)&As[k][ty * 4];
                *(float4*)bv = *(const float4*)&Bs[k][tx * 4];
                #pragma unroll
                for (int i = 0; i < 4; ++i)
                    #pragma unroll
                    for (int j = 0; j < 4; ++j) acc[i][j] += av[i] * bv[j];
            }
            __syncthreads();
        }
    }
    float p[4] = {0.f, 0.f, 0.f, 0.f};
    #pragma unroll
    for (int i = 0; i < 4; ++i) {
        const float wv = whq[m0 + ty * 4 + i];
        #pragma unroll
        for (int j = 0; j < 4; ++j) p[j] += wv * fast_tanh(acc3[i][j] + acc[i][j]);
    }
    #pragma unroll
    for (int j = 0; j < 4; ++j) red[ty][tx * 4 + j] = p[j];
    __syncthreads();
    if (f < BN) {
        float s = 0.f;
        #pragma unroll
        for (int r = 0; r < 16; ++r) s += red[r][f];
        atomicAdd(&logits[(size_t)b * N + n0 + f], s);
    }
}

// ---------------------------------------------------------------------------
extern "C" void kernel_launch(void* const* d_in, const int* in_sizes, int n_in,
                              void* d_out, int out_size, void* d_ws, size_t ws_size,
                              hipStream_t stream) {
    const float* z_robot = (const float*)d_in[0];
    const float* z_human = (const float*)d_in[1];
    const float* W_b     = (const float*)d_in[2];
    const float* W_q     = (const float*)d_in[3];
    const float* W_v     = (const float*)d_in[4];
    const float* w_hq    = (const float*)d_in[5];
    float* out = (float*)d_out;

    const int Bn = 32, S = 512, F = 512, T = 1024;
    float* attn_out = out;
    float* aq_out   = out + (size_t)Bn * S;
    float* C_out    = out + (size_t)Bn * S + (size_t)Bn * T;

    char* ws = (char*)d_ws;
    const size_t E2 = 33554432;  // bytes of one bf16 [32][1024][512] buffer

    // fast-path layout
    ushort* zhT_hi  = (ushort*)(ws);
    ushort* zhT_lo  = (ushort*)(ws + E2);
    ushort* zrT_hi  = (ushort*)(ws + 2 * E2);
    ushort* zrT_lo  = (ushort*)(ws + 3 * E2);
    ushort* auxT_hi = (ushort*)(ws + 4 * E2);
    ushort* auxT_lo = (ushort*)(ws + 5 * E2);
    ushort* C16     = (ushort*)(ws + 6 * E2);   // 2*E2 bytes
    ushort* aux2    = auxT_hi;                  // alias: auxT dead after G2
    ushort* Wb_hi   = (ushort*)(ws + 8 * E2);
    ushort* Wb_lo   = Wb_hi + 262144;
    ushort* Wq16    = Wb_hi + 524288;
    ushort* Wv16    = Wb_hi + 786432;
    float*  logitsF = (float*)(ws + 8 * E2 + 2097152);
    const size_t FAST_REQ = 8 * E2 + 2097152 + 131072;

    if (ws_size >= FAST_REQ) {
        hipMemsetAsync(logitsF, 0, (size_t)Bn * T * sizeof(float), stream);
        transpose_split_k<<<dim3(32, 16, Bn), dim3(32, 8), 0, stream>>>(z_human, zhT_hi, zhT_lo, 512, 1024);
        transpose_split_k<<<dim3(32, 16, Bn), dim3(32, 8), 0, stream>>>(z_robot, zrT_hi, zrT_lo, 512, 1024);
        convert_split_k<<<dim3(1024), dim3(256), 0, stream>>>(W_b, Wb_hi, Wb_lo, 262144);
        convert_split_k<<<dim3(1024), dim3(256), 0, stream>>>(W_q, Wq16, nullptr, 262144);
        convert_split_k<<<dim3(1024), dim3(256), 0, stream>>>(W_v, Wv16, nullptr, 262144);
        // G1: auxT[b][h][s] = (zh^T @ Wb^T): A=zhT [h][u], B(n=s,k=u)=Wb; split x3
        gemm_split<0><<<dim3(4, 8, Bn), dim3(256), 0, stream>>>(
            zhT_hi, zhT_lo, 524288, 512, Wb_hi, Wb_lo, 0, 512, 512,
            auxT_hi, auxT_lo, nullptr, nullptr, 512, 524288);
        // G2: C[b][t][h] = tanh(zr^T @ aux): A=zrT [t][s], B(n=h,k=s)=auxT; split x3
        gemm_split<1><<<dim3(8, 8, Bn), dim3(256), 0, stream>>>(
            zrT_hi, zrT_lo, 524288, 512, auxT_hi, auxT_lo, 524288, 512, 512,
            nullptr, nullptr, C_out, C16, 1024, 1048576);
        // G3: aux2[b][f][h] = Wv @ zh: A=Wv16 [f][u], B(n=h,k=u)=zhT_hi; plain
        gemm_plain_store<<<dim3(8, 4, Bn), dim3(256), 0, stream>>>(
            Wv16, 0, 512, zhT_hi, 524288, 512, 512, aux2, 524288, 1024);
        // G4: logits = sum_f whq*tanh(Wq@zr + aux2@C^T)
        gemm_fused_logits<<<dim3(8, 4, Bn), dim3(256), 0, stream>>>(
            Wq16, zrT_hi, aux2, C16, w_hq, logitsF);
        softmax_kernel<<<dim3(Bn), dim3(256), 0, stream>>>(logitsF, aq_out, T);
        attn_kernel<<<dim3(S / 4, Bn), dim3(256), 0, stream>>>(z_robot, aq_out, attn_out, S, T);
    } else {
        // fp32 fallback (round-1 path)
        float* ws0    = (float*)ws;
        float* logits = (float*)(ws + (size_t)Bn * S * T * 4);
        hipMemsetAsync(logits, 0, (size_t)Bn * T * sizeof(float), stream);
        dim3 blk(16, 16);
        gemm_nn<<<dim3(T / BN, S / BM, Bn), blk, 0, stream>>>(W_b, z_human, ws0, S, T, S);
        gemm_tn_tanh<<<dim3(T / BN, T / BM, Bn), blk, 0, stream>>>(z_robot, ws0, C_out, T, T, S);
        gemm_nn<<<dim3(T / BN, F / BM, Bn), blk, 0, stream>>>(W_v, z_human, ws0, F, T, S);
        gemm_nt_fused<<<dim3(T / BN, F / BM, Bn), blk, 0, stream>>>(
            W_q, z_robot, ws0, C_out, w_hq, logits, F, T, S, T);
        softmax_kernel<<<dim3(Bn), dim3(256), 0, stream>>>(logits, aq_out, T);
        attn_kernel<<<dim3(S / 4, Bn), dim3(256), 0, stream>>>(z_robot, aq_out, attn_out, S, T);
    }
}

// Round 3
// 580.721 us; speedup vs baseline: 3.1312x; 1.0457x over previous
//
#include <hip/hip_runtime.h>
#include <math.h>

// Content_Attn: B=32, S=512, F=512, T=1024, fp32 in/out.
// Outputs concat: attn [B,S,1] (16384), a_q [B,1,T] (32768), C [B,T,T] (33.5M).
//
// FAST path (needs ws >= ~271MB): MFMA bf16, split-precision (x3) for aux & C,
// plain bf16 for aux2/aux3/H_q/logits. Round 3: ping-pong LDS double-buffer,
// one barrier per K-step. FALLBACK: fp32 path (ws >= ~68MB).

using f32x4  = __attribute__((ext_vector_type(4))) float;
using bf16x8 = __attribute__((ext_vector_type(8))) short;

__device__ __forceinline__ ushort f2bf(float x) {
    uint u = __float_as_uint(x);
    return (ushort)((u + 0x7fffu + ((u >> 16) & 1u)) >> 16);  // RNE
}
__device__ __forceinline__ float bf2f(ushort h) { return __uint_as_float((uint)h << 16); }

__device__ __forceinline__ float fast_tanh(float x) {
    // tanh(x) = 1 - 2/(e^{2x}+1); overflow -> 1, underflow -> -1, no NaN.
    return 1.0f - 2.0f / (__expf(2.0f * x) + 1.0f);
}

// async global->LDS, 16B per lane; LDS dst = wave-uniform base + lane*16
__device__ __forceinline__ void gll16(const void* g, void* l) {
    __builtin_amdgcn_global_load_lds(
        (__attribute__((address_space(1))) void*)(void*)g,
        (__attribute__((address_space(3))) void*)l, 16, 0, 0);
}

// ---------------------------------------------------------------------------
// Conversion kernels
// ---------------------------------------------------------------------------

// in fp32 [b][R][Cn] -> hi/lo bf16 [b][Cn][R] (transpose + split)
__global__ __launch_bounds__(256)
void transpose_split_k(const float* __restrict__ in, ushort* __restrict__ hi,
                       ushort* __restrict__ lo, int R, int Cn) {
    __shared__ float tile[32][33];
    const int b = blockIdx.z;
    const float* inb = in + (size_t)b * R * Cn;
    const int c0 = blockIdx.x * 32, r0 = blockIdx.y * 32;
    const int tx = threadIdx.x, ty = threadIdx.y;  // 32 x 8
    #pragma unroll
    for (int i = 0; i < 32; i += 8)
        tile[ty + i][tx] = inb[(size_t)(r0 + ty + i) * Cn + c0 + tx];
    __syncthreads();
    const size_t ob = (size_t)b * R * Cn;
    #pragma unroll
    for (int i = 0; i < 32; i += 8) {
        const float v = tile[tx][ty + i];
        const ushort h = f2bf(v);
        const size_t o = ob + (size_t)(c0 + ty + i) * R + r0 + tx;
        hi[o] = h;
        lo[o] = f2bf(v - bf2f(h));
    }
}

// elementwise fp32 -> bf16 hi (+ optional lo)
__global__ __launch_bounds__(256)
void convert_split_k(const float* __restrict__ in, ushort* __restrict__ hi,
                     ushort* __restrict__ lo, int n) {
    const int i = blockIdx.x * 256 + threadIdx.x;
    if (i < n) {
        const float v = in[i];
        const ushort h = f2bf(v);
        hi[i] = h;
        if (lo) lo[i] = f2bf(v - bf2f(h));
    }
}

// ---------------------------------------------------------------------------
// Split-precision MFMA GEMM (BK=32, ping-pong dbuf): A[m][k], B[n][k].
// MODE 0: store result split (hi/lo bf16).  MODE 1: tanh -> fp32 + bf16.
// LDS: 2 stages x (Ahi|Alo|Bhi|Blo @ 4096 ushorts each) = 64KB.
// ---------------------------------------------------------------------------
template <int MODE>
__global__ __launch_bounds__(256, 2)
void gemm_split(const ushort* __restrict__ Ahi, const ushort* __restrict__ Alo,
                long sAb, int ldA,
                const ushort* __restrict__ Bhi, const ushort* __restrict__ Blo,
                long sBb, int ldB, int K,
                ushort* __restrict__ Ohi, ushort* __restrict__ Olo,
                float* __restrict__ Of, ushort* __restrict__ O16,
                int ldO, long sOb) {
    __shared__ __align__(16) ushort lds[32768];
    const int b = blockIdx.z, m0 = blockIdx.y * 128, n0 = blockIdx.x * 128;
    const int t = threadIdx.x, l = t & 63, w = t >> 6, wm = w >> 1, wn = w & 1;

    // staging: per inst 16 rows x 4 chunks(16B); source chunk XOR-swizzled
    const int srow = l >> 2;
    const int sch  = ((l & 3) ^ (srow & 3)) * 8;
    const ushort* pAh = Ahi + (long)b * sAb + (long)(m0 + w * 32 + srow) * ldA + sch;
    const ushort* pAl = Alo + (long)b * sAb + (long)(m0 + w * 32 + srow) * ldA + sch;
    const ushort* pBh = Bhi + (long)b * sBb + (long)(n0 + w * 32 + srow) * ldB + sch;
    const ushort* pBl = Blo + (long)b * sBb + (long)(n0 + w * 32 + srow) * ldB + sch;

    const int q = l >> 4;
    int offA[4], offB[4];
    #pragma unroll
    for (int i = 0; i < 4; ++i) {
        const int rA = wm * 64 + i * 16 + (l & 15);
        offA[i] = rA * 32 + (q ^ (rA & 3)) * 8;
        const int rB = wn * 64 + i * 16 + (l & 15);
        offB[i] = rB * 32 + (q ^ (rB & 3)) * 8;
    }

    auto stage = [&](int k0, int st) {
        const int base = st * 16384;
        #pragma unroll
        for (int tt = 0; tt < 2; ++tt) {
            const int lo_ = base + (w * 32 + tt * 16) * 32;
            gll16(pAh + (long)(tt * 16) * ldA + k0, lds + lo_);
            gll16(pAl + (long)(tt * 16) * ldA + k0, lds + 4096 + lo_);
            gll16(pBh + (long)(tt * 16) * ldB + k0, lds + 8192 + lo_);
            gll16(pBl + (long)(tt * 16) * ldB + k0, lds + 12288 + lo_);
        }
    };

    f32x4 acc[4][4] = {};
    stage(0, 0);
    int st = 0;
    for (int k0 = 0; k0 < K; k0 += 32) {
        __syncthreads();           // drains prev staging (issued 1 step ago)
        if (k0 + 32 < K) stage(k0 + 32, st ^ 1);
        const int base = st * 16384;
        bf16x8 ah[4], al4[4], bh[4], bl4[4];
        #pragma unroll
        for (int i = 0; i < 4; ++i) {
            ah[i]  = *(const bf16x8*)&lds[base + offA[i]];
            al4[i] = *(const bf16x8*)&lds[base + 4096 + offA[i]];
            bh[i]  = *(const bf16x8*)&lds[base + 8192 + offB[i]];
            bl4[i] = *(const bf16x8*)&lds[base + 12288 + offB[i]];
        }
        #pragma unroll
        for (int i = 0; i < 4; ++i)
            #pragma unroll
            for (int j = 0; j < 4; ++j) {
                acc[i][j] = __builtin_amdgcn_mfma_f32_16x16x32_bf16(ah[i],  bh[j],  acc[i][j], 0, 0, 0);
                acc[i][j] = __builtin_amdgcn_mfma_f32_16x16x32_bf16(ah[i],  bl4[j], acc[i][j], 0, 0, 0);
                acc[i][j] = __builtin_amdgcn_mfma_f32_16x16x32_bf16(al4[i], bh[j],  acc[i][j], 0, 0, 0);
            }
        st ^= 1;
    }

    const int cl = l & 15, rl = (l >> 4) * 4;
    #pragma unroll
    for (int i = 0; i < 4; ++i)
        #pragma unroll
        for (int r = 0; r < 4; ++r) {
            const long mg = m0 + wm * 64 + i * 16 + rl + r;
            #pragma unroll
            for (int j = 0; j < 4; ++j) {
                const int ng = n0 + wn * 64 + j * 16 + cl;
                const float v = acc[i][j][r];
                const long o = (long)b * sOb + mg * ldO + ng;
                if (MODE == 0) {
                    const ushort h = f2bf(v);
                    Ohi[o] = h;
                    Olo[o] = f2bf(v - bf2f(h));
                } else {
                    const float tv = fast_tanh(v);
                    Of[o] = tv;
                    O16[o] = f2bf(tv);
                }
            }
        }
}

// ---------------------------------------------------------------------------
// Plain bf16 MFMA core (BK=64, ping-pong dbuf). LDS: 2 stages x 32KB = 64KB.
// Ends with __syncthreads() so it can be called twice on the same LDS.
// ---------------------------------------------------------------------------
__device__ __forceinline__ void plain_core(
    const ushort* __restrict__ A, long sAb, int ldA,
    const ushort* __restrict__ B, long sBb, int ldB, int K,
    int b, int m0, int n0, ushort* lds, f32x4 (&acc)[4][4]) {
    const int t = threadIdx.x, l = t & 63, w = t >> 6, wm = w >> 1, wn = w & 1;
    const int srow = l >> 3;
    const int sch  = ((l & 7) ^ (srow & 7)) * 8;
    const ushort* pA = A + (long)b * sAb + (long)(m0 + w * 32 + srow) * ldA + sch;
    const ushort* pB = B + (long)b * sBb + (long)(n0 + w * 32 + srow) * ldB + sch;
    const int q = l >> 4;
    int offA[4], offB[4];
    #pragma unroll
    for (int i = 0; i < 4; ++i) {
        const int rA = wm * 64 + i * 16 + (l & 15);
        offA[i] = rA * 64 + (q ^ (rA & 7)) * 8;
        const int rB = wn * 64 + i * 16 + (l & 15);
        offB[i] = 8192 + rB * 64 + (q ^ (rB & 7)) * 8;
    }
    auto stage = [&](int k0, int st) {
        const int base = st * 16384;
        #pragma unroll
        for (int tt = 0; tt < 4; ++tt) {
            gll16(pA + (long)(tt * 8) * ldA + k0, lds + base + (w * 32 + tt * 8) * 64);
            gll16(pB + (long)(tt * 8) * ldB + k0, lds + base + 8192 + (w * 32 + tt * 8) * 64);
        }
    };
    stage(0, 0);
    int st = 0;
    for (int k0 = 0; k0 < K; k0 += 64) {
        __syncthreads();
        if (k0 + 64 < K) stage(k0 + 64, st ^ 1);
        const int base = st * 16384;
        #pragma unroll
        for (int s = 0; s < 2; ++s) {
            bf16x8 av[4], bv[4];
            #pragma unroll
            for (int i = 0; i < 4; ++i) {
                av[i] = *(const bf16x8*)&lds[base + (offA[i] ^ (s * 32))];
                bv[i] = *(const bf16x8*)&lds[base + (offB[i] ^ (s * 32))];
            }
            #pragma unroll
            for (int i = 0; i < 4; ++i)
                #pragma unroll
                for (int j = 0; j < 4; ++j)
                    acc[i][j] = __builtin_amdgcn_mfma_f32_16x16x32_bf16(av[i], bv[j], acc[i][j], 0, 0, 0);
        }
        st ^= 1;
    }
    __syncthreads();   // lds may be reused by caller / a second plain_core call
}

// G3: aux2 = Wv @ zh  (store bf16)
__global__ __launch_bounds__(256, 2)
void gemm_plain_store(const ushort* __restrict__ A, long sAb, int ldA,
                      const ushort* __restrict__ B, long sBb, int ldB, int K,
                      ushort* __restrict__ O, long sOb, int ldO) {
    __shared__ __align__(16) ushort lds[32768];
    const int b = blockIdx.z, m0 = blockIdx.y * 128, n0 = blockIdx.x * 128;
    f32x4 acc[4][4] = {};
    plain_core(A, sAb, ldA, B, sBb, ldB, K, b, m0, n0, lds, acc);
    const int t = threadIdx.x, l = t & 63, w = t >> 6, wm = w >> 1, wn = w & 1;
    const int cl = l & 15, rl = (l >> 4) * 4;
    #pragma unroll
    for (int i = 0; i < 4; ++i)
        #pragma unroll
        for (int r = 0; r < 4; ++r) {
            const long mg = m0 + wm * 64 + i * 16 + rl + r;
            #pragma unroll
            for (int j = 0; j < 4; ++j)
                O[(long)b * sOb + mg * ldO + n0 + wn * 64 + j * 16 + cl] = f2bf(acc[i][j][r]);
        }
}

// G4: acc = Wq@zr + aux2@C^T; H=tanh(acc); logits[t] += sum_f whq[f]*H[f][t]
__global__ __launch_bounds__(256, 2)
void gemm_fused_logits(const ushort* __restrict__ Wq16, const ushort* __restrict__ zrT,
                       const ushort* __restrict__ aux2, const ushort* __restrict__ C16,
                       const float* __restrict__ whq, float* __restrict__ logits) {
    __shared__ __align__(16) ushort lds[32768];
    const int b = blockIdx.z, m0 = blockIdx.y * 128, n0 = blockIdx.x * 128;
    f32x4 acc[4][4] = {};
    plain_core(Wq16, 0, 512, zrT, 524288, 512, 512, b, m0, n0, lds, acc);
    plain_core(aux2, 524288, 1024, C16, 1048576, 1024, 1024, b, m0, n0, lds, acc);
    const int t = threadIdx.x, l = t & 63, w = t >> 6, wm = w >> 1, wn = w & 1;
    float p[4] = {0.f, 0.f, 0.f, 0.f};
    #pragma unroll
    for (int i = 0; i < 4; ++i)
        #pragma unroll
        for (int r = 0; r < 4; ++r) {
            const float wv = whq[m0 + wm * 64 + i * 16 + (l >> 4) * 4 + r];
            #pragma unroll
            for (int j = 0; j < 4; ++j)
                p[j] += wv * fast_tanh(acc[i][j][r]);
        }
    #pragma unroll
    for (int j = 0; j < 4; ++j) {
        p[j] += __shfl_xor(p[j], 16);
        p[j] += __shfl_xor(p[j], 32);
    }
    float* red = (float*)lds;  // reuse LDS (reads drained by plain_core's tail barrier)
    if (l < 16) {
        #pragma unroll
        for (int j = 0; j < 4; ++j)
            red[wm * 128 + wn * 64 + j * 16 + l] = p[j];
    }
    __syncthreads();
    if (t < 128)
        atomicAdd(&logits[(long)b * 1024 + n0 + t], red[t] + red[128 + t]);
}

// ---------------------------------------------------------------------------
// Softmax + attn tail (shared by both paths)
// ---------------------------------------------------------------------------
__global__ __launch_bounds__(256)
void softmax_kernel(const float* __restrict__ logits, float* __restrict__ aq, int T) {
    __shared__ float sm[256];
    const int b = blockIdx.x, tid = threadIdx.x;
    float v[4];
    float mx = -1e30f;
    #pragma unroll
    for (int i = 0; i < 4; ++i) {
        v[i] = logits[(size_t)b * T + tid + 256 * i];
        mx = fmaxf(mx, v[i]);
    }
    sm[tid] = mx; __syncthreads();
    for (int s = 128; s > 0; s >>= 1) {
        if (tid < s) sm[tid] = fmaxf(sm[tid], sm[tid + s]);
        __syncthreads();
    }
    mx = sm[0]; __syncthreads();
    float e[4], sum = 0.f;
    #pragma unroll
    for (int i = 0; i < 4; ++i) { e[i] = __expf(v[i] - mx); sum += e[i]; }
    sm[tid] = sum; __syncthreads();
    for (int s = 128; s > 0; s >>= 1) {
        if (tid < s) sm[tid] += sm[tid + s];
        __syncthreads();
    }
    const float inv = 1.0f / sm[0];
    #pragma unroll
    for (int i = 0; i < 4; ++i)
        aq[(size_t)b * T + tid + 256 * i] = e[i] * inv;
}

__global__ __launch_bounds__(256)
void attn_kernel(const float* __restrict__ ZR, const float* __restrict__ aq,
                 float* __restrict__ out, int S, int T) {
    const int b = blockIdx.y;
    const int s = blockIdx.x * 4 + (threadIdx.x >> 6);
    const int lane = threadIdx.x & 63;
    const float* row = ZR + ((size_t)b * S + s) * T;
    const float* a = aq + (size_t)b * T;
    float sum = 0.f;
    for (int t = lane; t < T; t += 64) sum += row[t] * a[t];
    #pragma unroll
    for (int off = 32; off > 0; off >>= 1) sum += __shfl_down(sum, off, 64);
    if (lane == 0) out[(size_t)b * S + s] = sum;
}

// ---------------------------------------------------------------------------
// FALLBACK fp32 path (round-1 kernels, proven; needs ~68MB ws)
// ---------------------------------------------------------------------------
#define BM 64
#define BN 64
#define BK 16
#define PAD 4

__global__ __launch_bounds__(256)
void gemm_nn(const float* __restrict__ A, const float* __restrict__ Bm,
             float* __restrict__ D, int M, int N, int K) {
    __shared__ float As[BK][BM + PAD];
    __shared__ float Bs[BK][BN + PAD];
    const int b = blockIdx.z, m0 = blockIdx.y * BM, n0 = blockIdx.x * BN;
    const int tx = threadIdx.x, ty = threadIdx.y, f = ty * 16 + tx;
    const float* Bb = Bm + (size_t)b * K * N;
    float acc[4][4] = {};
    const int ka = f % 16, ma = f / 16, nb = f % 64, kb = f / 64;
    for (int k0 = 0; k0 < K; k0 += BK) {
        #pragma unroll
        for (int i = 0; i < 4; ++i)
            As[ka][ma + 16 * i] = A[(size_t)(m0 + ma + 16 * i) * K + k0 + ka];
        #pragma unroll
        for (int i = 0; i < 4; ++i)
            Bs[kb + 4 * i][nb] = Bb[(size_t)(k0 + kb + 4 * i) * N + n0 + nb];
        __syncthreads();
        #pragma unroll
        for (int k = 0; k < BK; ++k) {
            float av[4], bv[4];
            *(float4*)av = *(const float4*)&As[k][ty * 4];
            *(float4*)bv = *(const float4*)&Bs[k][tx * 4];
            #pragma unroll
            for (int i = 0; i < 4; ++i)
                #pragma unroll
                for (int j = 0; j < 4; ++j) acc[i][j] += av[i] * bv[j];
        }
        __syncthreads();
    }
    float* Db = D + (size_t)b * M * N;
    #pragma unroll
    for (int i = 0; i < 4; ++i)
        *(float4*)&Db[(size_t)(m0 + ty * 4 + i) * N + n0 + tx * 4] =
            make_float4(acc[i][0], acc[i][1], acc[i][2], acc[i][3]);
}

__global__ __launch_bounds__(256)
void gemm_tn_tanh(const float* __restrict__ ZR, const float* __restrict__ AUX,
                  float* __restrict__ C, int M, int N, int K) {
    __shared__ float As[BK][BM + PAD];
    __shared__ float Bs[BK][BN + PAD];
    const int b = blockIdx.z, m0 = blockIdx.y * BM, n0 = blockIdx.x * BN;
    const int tx = threadIdx.x, ty = threadIdx.y, f = ty * 16 + tx;
    const float* ZRb = ZR + (size_t)b * K * M;
    const float* AUXb = AUX + (size_t)b * K * N;
    float acc[4][4] = {};
    const int nl = f % 64, kl = f / 64;
    for (int k0 = 0; k0 < K; k0 += BK) {
        #pragma unroll
        for (int i = 0; i < 4; ++i)
            As[kl + 4 * i][nl] = ZRb[(size_t)(k0 + kl + 4 * i) * M + m0 + nl];
        #pragma unroll
        for (int i = 0; i < 4; ++i)
            Bs[kl + 4 * i][nl] = AUXb[(size_t)(k0 + kl + 4 * i) * N + n0 + nl];
        __syncthreads();
        #pragma unroll
        for (int k = 0; k < BK; ++k) {
            float av[4], bv[4];
            *(float4*)av = *(const float4*)&As[k][ty * 4];
            *(float4*)bv = *(const float4*)&Bs[k][tx * 4];
            #pragma unroll
            for (int i = 0; i < 4; ++i)
                #pragma unroll
                for (int j = 0; j < 4; ++j) acc[i][j] += av[i] * bv[j];
        }
        __syncthreads();
    }
    float* Cb = C + (size_t)b * M * N;
    #pragma unroll
    for (int i = 0; i < 4; ++i)
        *(float4*)&Cb[(size_t)(m0 + ty * 4 + i) * N + n0 + tx * 4] =
            make_float4(fast_tanh(acc[i][0]), fast_tanh(acc[i][1]),
                        fast_tanh(acc[i][2]), fast_tanh(acc[i][3]));
}

__global__ __launch_bounds__(256)
void gemm_nt_fused(const float* __restrict__ Wq, const float* __restrict__ ZR,
                   const float* __restrict__ A2, const float* __restrict__ Cm,
                   const float* __restrict__ whq, float* __restrict__ logits,
                   int M, int N, int K1, int K2) {
    __shared__ float As[BK][BM + PAD];
    __shared__ float Bs[BK][BN + PAD];
    __shared__ float red[16][BN];
    const int b = blockIdx.z, m0 = blockIdx.y * BM, n0 = blockIdx.x * BN;
    const int tx = threadIdx.x, ty = threadIdx.y, f = ty * 16 + tx;
    const float* ZRb = ZR + (size_t)b * K1 * N;
    const float* A2b = A2 + (size_t)b * M * K2;
    const float* Cb = Cm + (size_t)b * N * K2;
    float acc3[4][4] = {};
    {
        const int ka = f % 16, ma = f / 16, nb = f % 64, kb = f / 64;
        for (int k0 = 0; k0 < K1; k0 += BK) {
            #pragma unroll
            for (int i = 0; i < 4; ++i)
                As[ka][ma + 16 * i] = Wq[(size_t)(m0 + ma + 16 * i) * K1 + k0 + ka];
            #pragma unroll
            for (int i = 0; i < 4; ++i)
                Bs[kb + 4 * i][nb] = ZRb[(size_t)(k0 + kb + 4 * i) * N + n0 + nb];
            __syncthreads();
            #pragma unroll
            for (int k = 0; k < BK; ++k) {
                float av[4], bv[4];
                *(float4*)av = *(const float4*)&As[k][ty * 4];
                *(float4*)bv = *(const float4*)&Bs[k][tx * 4];
                #pragma unroll
                for (int i = 0; i < 4; ++i)
                    #pragma unroll
                    for (int j = 0; j < 4; ++j) acc3[i][j] += av[i] * bv[j];
            }
            __syncthreads();
        }
    }
    float acc[4][4] = {};
    {
        const int ka = f % 16, ra = f / 16;
        for (int k0 = 0; k0 < K2; k0 += BK) {
            #pragma unroll
            for (int i = 0; i < 4; ++i)
                As[ka][ra + 16 * i] = A2b[(size_t)(m0 + ra + 16 * i) * K2 + k0 + ka];
            #pragma unroll
            for (int i = 0; i < 4; ++i)
                Bs[ka][ra + 16 * i] = Cb[(size_t)(n0 + ra + 16 * i) * K2 + k0 + ka];
            __syncthreads();
            #pragma unroll
            for (int k = 0; k < BK; ++k) {
                float av[4], bv[4];
                *(float4*)av = *(const float4*)&As[k][ty * 4];
                *(float4*)bv = *(const float4*)&Bs[k][tx * 4];
                #pragma unroll
                for (int i = 0; i < 4; ++i)
                    #pragma unroll
                    for (int j = 0; j < 4; ++j) acc[i][j] += av[i] * bv[j];
            }
            __syncthreads();
        }
    }
    float p[4] = {0.f, 0.f, 0.f, 0.f};
    #pragma unroll
    for (int i = 0; i < 4; ++i) {
        const float wv = whq[m0 + ty * 4 + i];
        #pragma unroll
        for (int j = 0; j < 4; ++j) p[j] += wv * fast_tanh(acc3[i][j] + acc[i][j]);
    }
    #pragma unroll
    for (int j = 0; j < 4; ++j) red[ty][tx * 4 + j] = p[j];
    __syncthreads();
    if (f < BN) {
        float s = 0.f;
        #pragma unroll
        for (int r = 0; r < 16; ++r) s += red[r][f];
        atomicAdd(&logits[(size_t)b * N + n0 + f], s);
    }
}

// ---------------------------------------------------------------------------
extern "C" void kernel_launch(void* const* d_in, const int* in_sizes, int n_in,
                              void* d_out, int out_size, void* d_ws, size_t ws_size,
                              hipStream_t stream) {
    const float* z_robot = (const float*)d_in[0];
    const float* z_human = (const float*)d_in[1];
    const float* W_b     = (const float*)d_in[2];
    const float* W_q     = (const float*)d_in[3];
    const float* W_v     = (const float*)d_in[4];
    const float* w_hq    = (const float*)d_in[5];
    float* out = (float*)d_out;

    const int Bn = 32, S = 512, F = 512, T = 1024;
    float* attn_out = out;
    float* aq_out   = out + (size_t)Bn * S;
    float* C_out    = out + (size_t)Bn * S + (size_t)Bn * T;

    char* ws = (char*)d_ws;
    const size_t E2 = 33554432;  // bytes of one bf16 [32][1024][512] buffer

    // fast-path layout
    ushort* zhT_hi  = (ushort*)(ws);
    ushort* zhT_lo  = (ushort*)(ws + E2);
    ushort* zrT_hi  = (ushort*)(ws + 2 * E2);
    ushort* zrT_lo  = (ushort*)(ws + 3 * E2);
    ushort* auxT_hi = (ushort*)(ws + 4 * E2);
    ushort* auxT_lo = (ushort*)(ws + 5 * E2);
    ushort* C16     = (ushort*)(ws + 6 * E2);   // 2*E2 bytes
    ushort* aux2    = auxT_hi;                  // alias: auxT dead after G2
    ushort* Wb_hi   = (ushort*)(ws + 8 * E2);
    ushort* Wb_lo   = Wb_hi + 262144;
    ushort* Wq16    = Wb_hi + 524288;
    ushort* Wv16    = Wb_hi + 786432;
    float*  logitsF = (float*)(ws + 8 * E2 + 2097152);
    const size_t FAST_REQ = 8 * E2 + 2097152 + 131072;

    if (ws_size >= FAST_REQ) {
        hipMemsetAsync(logitsF, 0, (size_t)Bn * T * sizeof(float), stream);
        transpose_split_k<<<dim3(32, 16, Bn), dim3(32, 8), 0, stream>>>(z_human, zhT_hi, zhT_lo, 512, 1024);
        transpose_split_k<<<dim3(32, 16, Bn), dim3(32, 8), 0, stream>>>(z_robot, zrT_hi, zrT_lo, 512, 1024);
        convert_split_k<<<dim3(1024), dim3(256), 0, stream>>>(W_b, Wb_hi, Wb_lo, 262144);
        convert_split_k<<<dim3(1024), dim3(256), 0, stream>>>(W_q, Wq16, nullptr, 262144);
        convert_split_k<<<dim3(1024), dim3(256), 0, stream>>>(W_v, Wv16, nullptr, 262144);
        // G1: auxT[b][h][s] = (zh^T @ Wb^T): A=zhT [h][u], B(n=s,k=u)=Wb; split x3
        gemm_split<0><<<dim3(4, 8, Bn), dim3(256), 0, stream>>>(
            zhT_hi, zhT_lo, 524288, 512, Wb_hi, Wb_lo, 0, 512, 512,
            auxT_hi, auxT_lo, nullptr, nullptr, 512, 524288);
        // G2: C[b][t][h] = tanh(zr^T @ aux): A=zrT [t][s], B(n=h,k=s)=auxT; split x3
        gemm_split<1><<<dim3(8, 8, Bn), dim3(256), 0, stream>>>(
            zrT_hi, zrT_lo, 524288, 512, auxT_hi, auxT_lo, 524288, 512, 512,
            nullptr, nullptr, C_out, C16, 1024, 1048576);
        // G3: aux2[b][f][h] = Wv @ zh: A=Wv16 [f][u], B(n=h,k=u)=zhT_hi; plain
        gemm_plain_store<<<dim3(8, 4, Bn), dim3(256), 0, stream>>>(
            Wv16, 0, 512, zhT_hi, 524288, 512, 512, aux2, 524288, 1024);
        // G4: logits = sum_f whq*tanh(Wq@zr + aux2@C^T)
        gemm_fused_logits<<<dim3(8, 4, Bn), dim3(256), 0, stream>>>(
            Wq16, zrT_hi, aux2, C16, w_hq, logitsF);
        softmax_kernel<<<dim3(Bn), dim3(256), 0, stream>>>(logitsF, aq_out, T);
        attn_kernel<<<dim3(S / 4, Bn), dim3(256), 0, stream>>>(z_robot, aq_out, attn_out, S, T);
    } else {
        // fp32 fallback (round-1 path)
        float* ws0    = (float*)ws;
        float* logits = (float*)(ws + (size_t)Bn * S * T * 4);
        hipMemsetAsync(logits, 0, (size_t)Bn * T * sizeof(float), stream);
        dim3 blk(16, 16);
        gemm_nn<<<dim3(T / BN, S / BM, Bn), blk, 0, stream>>>(W_b, z_human, ws0, S, T, S);
        gemm_tn_tanh<<<dim3(T / BN, T / BM, Bn), blk, 0, stream>>>(z_robot, ws0, C_out, T, T, S);
        gemm_nn<<<dim3(T / BN, F / BM, Bn), blk, 0, stream>>>(W_v, z_human, ws0, F, T, S);
        gemm_nt_fused<<<dim3(T / BN, F / BM, Bn), blk, 0, stream>>>(
            W_q, z_robot, ws0, C_out, w_hq, logits, F, T, S, T);
        softmax_kernel<<<dim3(Bn), dim3(256), 0, stream>>>(logits, aq_out, T);
        attn_kernel<<<dim3(S / 4, Bn), dim3(256), 0, stream>>>(z_robot, aq_out, attn_out, S, T);
    }
}

// Round 4
// 558.255 us; speedup vs baseline: 3.2572x; 1.0402x over previous
//
#include <hip/hip_runtime.h>
#include <math.h>

// Content_Attn: B=32, S=512, F=512, T=1024, fp32 in/out.
// Outputs concat: attn [B,S,1], a_q [B,1,T], C [B,T,T].
//
// FAST path (ws >= ~271MB): MFMA bf16, split-precision (x3) for aux & C, plain
// bf16 downstream. Round 4: XCD-affine batch swizzle (one batch's 4MB working
// set pinned to one XCD's L2), fused vectorized transposes, merged converts.
// FALLBACK: fp32 path (ws >= ~68MB).

using f32x4  = __attribute__((ext_vector_type(4))) float;
using bf16x8 = __attribute__((ext_vector_type(8))) short;

__device__ __forceinline__ ushort f2bf(float x) {
    uint u = __float_as_uint(x);
    return (ushort)((u + 0x7fffu + ((u >> 16) & 1u)) >> 16);  // RNE
}
__device__ __forceinline__ float bf2f(ushort h) { return __uint_as_float((uint)h << 16); }

__device__ __forceinline__ float fast_tanh(float x) {
    return 1.0f - 2.0f / (__expf(2.0f * x) + 1.0f);
}

// async global->LDS, 16B per lane; LDS dst = wave-uniform base + lane*16
__device__ __forceinline__ void gll16(const void* g, void* l) {
    __builtin_amdgcn_global_load_lds(
        (__attribute__((address_space(1))) void*)(void*)g,
        (__attribute__((address_space(3))) void*)l, 16, 0, 0);
}

// XCD-affine decode: all tiles of one batch land on one XCD (id%8 heuristic).
// total blocks = 32 * tiles_pb; batches = 32, XCDs = 8.
__device__ __forceinline__ void xcd_decode(int id, int tiles_pb, int ntx,
                                           int& batch, int& m0, int& n0) {
    const int xcd = id & 7, slot = id >> 3;
    batch = (slot / tiles_pb) * 8 + xcd;
    const int tile = slot % tiles_pb;
    m0 = (tile / ntx) * 128;
    n0 = (tile % ntx) * 128;
}

// ---------------------------------------------------------------------------
// Transposes + conversions
// ---------------------------------------------------------------------------

// both z tensors: fp32 [b][512][1024] -> hi/lo bf16 [b][1024][512]
// block: 64(R) x 32(C) tile; ushort2 stores (coalesced 4B/lane).
__global__ __launch_bounds__(256)
void transpose_split2_k(const float* __restrict__ inA, ushort* __restrict__ hiA,
                        ushort* __restrict__ loA,
                        const float* __restrict__ inB, ushort* __restrict__ hiB,
                        ushort* __restrict__ loB) {
    __shared__ float tile[32][65];  // [c][r]
    const int z = blockIdx.z;           // 0..63
    const int b = z & 31, which = z >> 5;
    const float* in = (which ? inB : inA) + (size_t)b * 512 * 1024;
    ushort* hi = (which ? hiB : hiA) + (size_t)b * 512 * 1024;
    ushort* lo = (which ? loB : loA) + (size_t)b * 512 * 1024;
    const int c0 = blockIdx.x * 32, r0 = blockIdx.y * 64;
    const int tx = threadIdx.x, ty = threadIdx.y;  // 32 x 8
    #pragma unroll
    for (int i = 0; i < 8; ++i)
        tile[tx][ty + 8 * i] = in[(size_t)(r0 + ty + 8 * i) * 1024 + c0 + tx];
    __syncthreads();
    #pragma unroll
    for (int j = 0; j < 4; ++j) {
        const int c = ty + 8 * j;
        const float v0 = tile[c][2 * tx], v1 = tile[c][2 * tx + 1];
        const ushort h0 = f2bf(v0), h1 = f2bf(v1);
        const size_t o = (size_t)(c0 + c) * 512 + r0 + 2 * tx;
        *(ushort2*)&hi[o] = make_ushort2(h0, h1);
        *(ushort2*)&lo[o] = make_ushort2(f2bf(v0 - bf2f(h0)), f2bf(v1 - bf2f(h1)));
    }
}

// Wb (split) + Wq + Wv (hi only), one launch. n = 3*262144.
__global__ __launch_bounds__(256)
void convert_weights_k(const float* __restrict__ Wb, const float* __restrict__ Wq,
                       const float* __restrict__ Wv, ushort* __restrict__ Wb_hi,
                       ushort* __restrict__ Wb_lo, ushort* __restrict__ Wq16,
                       ushort* __restrict__ Wv16) {
    const int i = blockIdx.x * 256 + threadIdx.x;
    const int seg = i >> 18, off = i & 262143;   // 262144 = 2^18
    if (seg == 0) {
        const float v = Wb[off];
        const ushort h = f2bf(v);
        Wb_hi[off] = h;
        Wb_lo[off] = f2bf(v - bf2f(h));
    } else if (seg == 1) {
        Wq16[off] = f2bf(Wq[off]);
    } else {
        Wv16[off] = f2bf(Wv[off]);
    }
}

// ---------------------------------------------------------------------------
// Split-precision MFMA GEMM (BK=32, ping-pong dbuf): A[m][k], B[n][k].
// MODE 0: store split (hi/lo).  MODE 1: tanh -> fp32 + bf16.
// ---------------------------------------------------------------------------
template <int MODE>
__global__ __launch_bounds__(256, 2)
void gemm_split(const ushort* __restrict__ Ahi, const ushort* __restrict__ Alo,
                long sAb, int ldA,
                const ushort* __restrict__ Bhi, const ushort* __restrict__ Blo,
                long sBb, int ldB, int K,
                ushort* __restrict__ Ohi, ushort* __restrict__ Olo,
                float* __restrict__ Of, ushort* __restrict__ O16,
                int ldO, long sOb, int tiles_pb, int ntx) {
    __shared__ __align__(16) ushort lds[32768];
    int b, m0, n0;
    xcd_decode(blockIdx.x, tiles_pb, ntx, b, m0, n0);
    const int t = threadIdx.x, l = t & 63, w = t >> 6, wm = w >> 1, wn = w & 1;

    const int srow = l >> 2;
    const int sch  = ((l & 3) ^ (srow & 3)) * 8;
    const ushort* pAh = Ahi + (long)b * sAb + (long)(m0 + w * 32 + srow) * ldA + sch;
    const ushort* pAl = Alo + (long)b * sAb + (long)(m0 + w * 32 + srow) * ldA + sch;
    const ushort* pBh = Bhi + (long)b * sBb + (long)(n0 + w * 32 + srow) * ldB + sch;
    const ushort* pBl = Blo + (long)b * sBb + (long)(n0 + w * 32 + srow) * ldB + sch;

    const int q = l >> 4;
    int offA[4], offB[4];
    #pragma unroll
    for (int i = 0; i < 4; ++i) {
        const int rA = wm * 64 + i * 16 + (l & 15);
        offA[i] = rA * 32 + (q ^ (rA & 3)) * 8;
        const int rB = wn * 64 + i * 16 + (l & 15);
        offB[i] = rB * 32 + (q ^ (rB & 3)) * 8;
    }

    auto stage = [&](int k0, int st) {
        const int base = st * 16384;
        #pragma unroll
        for (int tt = 0; tt < 2; ++tt) {
            const int lo_ = base + (w * 32 + tt * 16) * 32;
            gll16(pAh + (long)(tt * 16) * ldA + k0, lds + lo_);
            gll16(pAl + (long)(tt * 16) * ldA + k0, lds + 4096 + lo_);
            gll16(pBh + (long)(tt * 16) * ldB + k0, lds + 8192 + lo_);
            gll16(pBl + (long)(tt * 16) * ldB + k0, lds + 12288 + lo_);
        }
    };

    f32x4 acc[4][4] = {};
    stage(0, 0);
    int st = 0;
    for (int k0 = 0; k0 < K; k0 += 32) {
        __syncthreads();
        if (k0 + 32 < K) stage(k0 + 32, st ^ 1);
        const int base = st * 16384;
        bf16x8 ah[4], al4[4], bh[4], bl4[4];
        #pragma unroll
        for (int i = 0; i < 4; ++i) {
            ah[i]  = *(const bf16x8*)&lds[base + offA[i]];
            al4[i] = *(const bf16x8*)&lds[base + 4096 + offA[i]];
            bh[i]  = *(const bf16x8*)&lds[base + 8192 + offB[i]];
            bl4[i] = *(const bf16x8*)&lds[base + 12288 + offB[i]];
        }
        #pragma unroll
        for (int i = 0; i < 4; ++i)
            #pragma unroll
            for (int j = 0; j < 4; ++j) {
                acc[i][j] = __builtin_amdgcn_mfma_f32_16x16x32_bf16(ah[i],  bh[j],  acc[i][j], 0, 0, 0);
                acc[i][j] = __builtin_amdgcn_mfma_f32_16x16x32_bf16(ah[i],  bl4[j], acc[i][j], 0, 0, 0);
                acc[i][j] = __builtin_amdgcn_mfma_f32_16x16x32_bf16(al4[i], bh[j],  acc[i][j], 0, 0, 0);
            }
        st ^= 1;
    }

    const int cl = l & 15, rl = (l >> 4) * 4;
    #pragma unroll
    for (int i = 0; i < 4; ++i)
        #pragma unroll
        for (int r = 0; r < 4; ++r) {
            const long mg = m0 + wm * 64 + i * 16 + rl + r;
            #pragma unroll
            for (int j = 0; j < 4; ++j) {
                const int ng = n0 + wn * 64 + j * 16 + cl;
                const float v = acc[i][j][r];
                const long o = (long)b * sOb + mg * ldO + ng;
                if (MODE == 0) {
                    const ushort h = f2bf(v);
                    Ohi[o] = h;
                    Olo[o] = f2bf(v - bf2f(h));
                } else {
                    const float tv = fast_tanh(v);
                    Of[o] = tv;
                    O16[o] = f2bf(tv);
                }
            }
        }
}

// ---------------------------------------------------------------------------
// Plain bf16 MFMA core (BK=64, ping-pong dbuf). Tail barrier for LDS reuse.
// ---------------------------------------------------------------------------
__device__ __forceinline__ void plain_core(
    const ushort* __restrict__ A, long sAb, int ldA,
    const ushort* __restrict__ B, long sBb, int ldB, int K,
    int b, int m0, int n0, ushort* lds, f32x4 (&acc)[4][4]) {
    const int t = threadIdx.x, l = t & 63, w = t >> 6, wm = w >> 1, wn = w & 1;
    const int srow = l >> 3;
    const int sch  = ((l & 7) ^ (srow & 7)) * 8;
    const ushort* pA = A + (long)b * sAb + (long)(m0 + w * 32 + srow) * ldA + sch;
    const ushort* pB = B + (long)b * sBb + (long)(n0 + w * 32 + srow) * ldB + sch;
    const int q = l >> 4;
    int offA[4], offB[4];
    #pragma unroll
    for (int i = 0; i < 4; ++i) {
        const int rA = wm * 64 + i * 16 + (l & 15);
        offA[i] = rA * 64 + (q ^ (rA & 7)) * 8;
        const int rB = wn * 64 + i * 16 + (l & 15);
        offB[i] = 8192 + rB * 64 + (q ^ (rB & 7)) * 8;
    }
    auto stage = [&](int k0, int st) {
        const int base = st * 16384;
        #pragma unroll
        for (int tt = 0; tt < 4; ++tt) {
            gll16(pA + (long)(tt * 8) * ldA + k0, lds + base + (w * 32 + tt * 8) * 64);
            gll16(pB + (long)(tt * 8) * ldB + k0, lds + base + 8192 + (w * 32 + tt * 8) * 64);
        }
    };
    stage(0, 0);
    int st = 0;
    for (int k0 = 0; k0 < K; k0 += 64) {
        __syncthreads();
        if (k0 + 64 < K) stage(k0 + 64, st ^ 1);
        const int base = st * 16384;
        #pragma unroll
        for (int s = 0; s < 2; ++s) {
            bf16x8 av[4], bv[4];
            #pragma unroll
            for (int i = 0; i < 4; ++i) {
                av[i] = *(const bf16x8*)&lds[base + (offA[i] ^ (s * 32))];
                bv[i] = *(const bf16x8*)&lds[base + (offB[i] ^ (s * 32))];
            }
            #pragma unroll
            for (int i = 0; i < 4; ++i)
                #pragma unroll
                for (int j = 0; j < 4; ++j)
                    acc[i][j] = __builtin_amdgcn_mfma_f32_16x16x32_bf16(av[i], bv[j], acc[i][j], 0, 0, 0);
        }
        st ^= 1;
    }
    __syncthreads();
}

// G3: aux2 = Wv @ zh  (store bf16)
__global__ __launch_bounds__(256, 2)
void gemm_plain_store(const ushort* __restrict__ A, long sAb, int ldA,
                      const ushort* __restrict__ B, long sBb, int ldB, int K,
                      ushort* __restrict__ O, long sOb, int ldO,
                      int tiles_pb, int ntx) {
    __shared__ __align__(16) ushort lds[32768];
    int b, m0, n0;
    xcd_decode(blockIdx.x, tiles_pb, ntx, b, m0, n0);
    f32x4 acc[4][4] = {};
    plain_core(A, sAb, ldA, B, sBb, ldB, K, b, m0, n0, lds, acc);
    const int t = threadIdx.x, l = t & 63, w = t >> 6, wm = w >> 1, wn = w & 1;
    const int cl = l & 15, rl = (l >> 4) * 4;
    #pragma unroll
    for (int i = 0; i < 4; ++i)
        #pragma unroll
        for (int r = 0; r < 4; ++r) {
            const long mg = m0 + wm * 64 + i * 16 + rl + r;
            #pragma unroll
            for (int j = 0; j < 4; ++j)
                O[(long)b * sOb + mg * ldO + n0 + wn * 64 + j * 16 + cl] = f2bf(acc[i][j][r]);
        }
}

// G4: acc = Wq@zr + aux2@C^T; H=tanh(acc); logits[t] += sum_f whq[f]*H[f][t]
__global__ __launch_bounds__(256, 2)
void gemm_fused_logits(const ushort* __restrict__ Wq16, const ushort* __restrict__ zrT,
                       const ushort* __restrict__ aux2, const ushort* __restrict__ C16,
                       const float* __restrict__ whq, float* __restrict__ logits,
                       int tiles_pb, int ntx) {
    __shared__ __align__(16) ushort lds[32768];
    int b, m0, n0;
    xcd_decode(blockIdx.x, tiles_pb, ntx, b, m0, n0);
    f32x4 acc[4][4] = {};
    plain_core(Wq16, 0, 512, zrT, 524288, 512, 512, b, m0, n0, lds, acc);
    plain_core(aux2, 524288, 1024, C16, 1048576, 1024, 1024, b, m0, n0, lds, acc);
    const int t = threadIdx.x, l = t & 63, w = t >> 6, wm = w >> 1, wn = w & 1;
    float p[4] = {0.f, 0.f, 0.f, 0.f};
    #pragma unroll
    for (int i = 0; i < 4; ++i)
        #pragma unroll
        for (int r = 0; r < 4; ++r) {
            const float wv = whq[m0 + wm * 64 + i * 16 + (l >> 4) * 4 + r];
            #pragma unroll
            for (int j = 0; j < 4; ++j)
                p[j] += wv * fast_tanh(acc[i][j][r]);
        }
    #pragma unroll
    for (int j = 0; j < 4; ++j) {
        p[j] += __shfl_xor(p[j], 16);
        p[j] += __shfl_xor(p[j], 32);
    }
    float* red = (float*)lds;
    if (l < 16) {
        #pragma unroll
        for (int j = 0; j < 4; ++j)
            red[wm * 128 + wn * 64 + j * 16 + l] = p[j];
    }
    __syncthreads();
    if (t < 128)
        atomicAdd(&logits[(long)b * 1024 + n0 + t], red[t] + red[128 + t]);
}

// ---------------------------------------------------------------------------
// Softmax + attn tail
// ---------------------------------------------------------------------------
__global__ __launch_bounds__(256)
void softmax_kernel(const float* __restrict__ logits, float* __restrict__ aq, int T) {
    __shared__ float sm[256];
    const int b = blockIdx.x, tid = threadIdx.x;
    float v[4];
    float mx = -1e30f;
    #pragma unroll
    for (int i = 0; i < 4; ++i) {
        v[i] = logits[(size_t)b * T + tid + 256 * i];
        mx = fmaxf(mx, v[i]);
    }
    sm[tid] = mx; __syncthreads();
    for (int s = 128; s > 0; s >>= 1) {
        if (tid < s) sm[tid] = fmaxf(sm[tid], sm[tid + s]);
        __syncthreads();
    }
    mx = sm[0]; __syncthreads();
    float e[4], sum = 0.f;
    #pragma unroll
    for (int i = 0; i < 4; ++i) { e[i] = __expf(v[i] - mx); sum += e[i]; }
    sm[tid] = sum; __syncthreads();
    for (int s = 128; s > 0; s >>= 1) {
        if (tid < s) sm[tid] += sm[tid + s];
        __syncthreads();
    }
    const float inv = 1.0f / sm[0];
    #pragma unroll
    for (int i = 0; i < 4; ++i)
        aq[(size_t)b * T + tid + 256 * i] = e[i] * inv;
}

__global__ __launch_bounds__(256)
void attn_kernel(const float* __restrict__ ZR, const float* __restrict__ aq,
                 float* __restrict__ out, int S, int T) {
    const int b = blockIdx.y;
    const int s = blockIdx.x * 4 + (threadIdx.x >> 6);
    const int lane = threadIdx.x & 63;
    const float* row = ZR + ((size_t)b * S + s) * T;
    const float* a = aq + (size_t)b * T;
    float sum = 0.f;
    for (int t = lane; t < T; t += 64) sum += row[t] * a[t];
    #pragma unroll
    for (int off = 32; off > 0; off >>= 1) sum += __shfl_down(sum, off, 64);
    if (lane == 0) out[(size_t)b * S + s] = sum;
}

// ---------------------------------------------------------------------------
// FALLBACK fp32 path (round-1 kernels, proven)
// ---------------------------------------------------------------------------
#define BM 64
#define BN 64
#define BK 16
#define PAD 4

__global__ __launch_bounds__(256)
void gemm_nn(const float* __restrict__ A, const float* __restrict__ Bm,
             float* __restrict__ D, int M, int N, int K) {
    __shared__ float As[BK][BM + PAD];
    __shared__ float Bs[BK][BN + PAD];
    const int b = blockIdx.z, m0 = blockIdx.y * BM, n0 = blockIdx.x * BN;
    const int tx = threadIdx.x, ty = threadIdx.y, f = ty * 16 + tx;
    const float* Bb = Bm + (size_t)b * K * N;
    float acc[4][4] = {};
    const int ka = f % 16, ma = f / 16, nb = f % 64, kb = f / 64;
    for (int k0 = 0; k0 < K; k0 += BK) {
        #pragma unroll
        for (int i = 0; i < 4; ++i)
            As[ka][ma + 16 * i] = A[(size_t)(m0 + ma + 16 * i) * K + k0 + ka];
        #pragma unroll
        for (int i = 0; i < 4; ++i)
            Bs[kb + 4 * i][nb] = Bb[(size_t)(k0 + kb + 4 * i) * N + n0 + nb];
        __syncthreads();
        #pragma unroll
        for (int k = 0; k < BK; ++k) {
            float av[4], bv[4];
            *(float4*)av = *(const float4*)&As[k][ty * 4];
            *(float4*)bv = *(const float4*)&Bs[k][tx * 4];
            #pragma unroll
            for (int i = 0; i < 4; ++i)
                #pragma unroll
                for (int j = 0; j < 4; ++j) acc[i][j] += av[i] * bv[j];
        }
        __syncthreads();
    }
    float* Db = D + (size_t)b * M * N;
    #pragma unroll
    for (int i = 0; i < 4; ++i)
        *(float4*)&Db[(size_t)(m0 + ty * 4 + i) * N + n0 + tx * 4] =
            make_float4(acc[i][0], acc[i][1], acc[i][2], acc[i][3]);
}

__global__ __launch_bounds__(256)
void gemm_tn_tanh(const float* __restrict__ ZR, const float* __restrict__ AUX,
                  float* __restrict__ C, int M, int N, int K) {
    __shared__ float As[BK][BM + PAD];
    __shared__ float Bs[BK][BN + PAD];
    const int b = blockIdx.z, m0 = blockIdx.y * BM, n0 = blockIdx.x * BN;
    const int tx = threadIdx.x, ty = threadIdx.y, f = ty * 16 + tx;
    const float* ZRb = ZR + (size_t)b * K * M;
    const float* AUXb = AUX + (size_t)b * K * N;
    float acc[4][4] = {};
    const int nl = f % 64, kl = f / 64;
    for (int k0 = 0; k0 < K; k0 += BK) {
        #pragma unroll
        for (int i = 0; i < 4; ++i)
            As[kl + 4 * i][nl] = ZRb[(size_t)(k0 + kl + 4 * i) * M + m0 + nl];
        #pragma unroll
        for (int i = 0; i < 4; ++i)
            Bs[kl + 4 * i][nl] = AUXb[(size_t)(k0 + kl + 4 * i) * N + n0 + nl];
        __syncthreads();
        #pragma unroll
        for (int k = 0; k < BK; ++k) {
            float av[4], bv[4];
            *(float4*)av = *(const float4*)&As[k][ty * 4];
            *(float4*)bv = *(const float4*)&Bs[k][tx * 4];
            #pragma unroll
            for (int i = 0; i < 4; ++i)
                #pragma unroll
                for (int j = 0; j < 4; ++j) acc[i][j] += av[i] * bv[j];
        }
        __syncthreads();
    }
    float* Cb = C + (size_t)b * M * N;
    #pragma unroll
    for (int i = 0; i < 4; ++i)
        *(float4*)&Cb[(size_t)(m0 + ty * 4 + i) * N + n0 + tx * 4] =
            make_float4(fast_tanh(acc[i][0]), fast_tanh(acc[i][1]),
                        fast_tanh(acc[i][2]), fast_tanh(acc[i][3]));
}

__global__ __launch_bounds__(256)
void gemm_nt_fused(const float* __restrict__ Wq, const float* __restrict__ ZR,
                   const float* __restrict__ A2, const float* __restrict__ Cm,
                   const float* __restrict__ whq, float* __restrict__ logits,
                   int M, int N, int K1, int K2) {
    __shared__ float As[BK][BM + PAD];
    __shared__ float Bs[BK][BN + PAD];
    __shared__ float red[16][BN];
    const int b = blockIdx.z, m0 = blockIdx.y * BM, n0 = blockIdx.x * BN;
    const int tx = threadIdx.x, ty = threadIdx.y, f = ty * 16 + tx;
    const float* ZRb = ZR + (size_t)b * K1 * N;
    const float* A2b = A2 + (size_t)b * M * K2;
    const float* Cb = Cm + (size_t)b * N * K2;
    float acc3[4][4] = {};
    {
        const int ka = f % 16, ma = f / 16, nb = f % 64, kb = f / 64;
        for (int k0 = 0; k0 < K1; k0 += BK) {
            #pragma unroll
            for (int i = 0; i < 4; ++i)
                As[ka][ma + 16 * i] = Wq[(size_t)(m0 + ma + 16 * i) * K1 + k0 + ka];
            #pragma unroll
            for (int i = 0; i < 4; ++i)
                Bs[kb + 4 * i][nb] = ZRb[(size_t)(k0 + kb + 4 * i) * N + n0 + nb];
            __syncthreads();
            #pragma unroll
            for (int k = 0; k < BK; ++k) {
                float av[4], bv[4];
                *(float4*)av = *(const float4*)&As[k][ty * 4];
                *(float4*)bv = *(const float4*)&Bs[k][tx * 4];
                #pragma unroll
                for (int i = 0; i < 4; ++i)
                    #pragma unroll
                    for (int j = 0; j < 4; ++j) acc3[i][j] += av[i] * bv[j];
            }
            __syncthreads();
        }
    }
    float acc[4][4] = {};
    {
        const int ka = f % 16, ra = f / 16;
        for (int k0 = 0; k0 < K2; k0 += BK) {
            #pragma unroll
            for (int i = 0; i < 4; ++i)
                As[ka][ra + 16 * i] = A2b[(size_t)(m0 + ra + 16 * i) * K2 + k0 + ka];
            #pragma unroll
            for (int i = 0; i < 4; ++i)
                Bs[ka][ra + 16 * i] = Cb[(size_t)(n0 + ra + 16 * i) * K2 + k0 + ka];
            __syncthreads();
            #pragma unroll
            for (int k = 0; k < BK; ++k) {
                float av[4], bv[4];
                *(float4*)av = *(const float4*)&As[k][ty * 4];
                *(float4*)bv = *(const float4*)&Bs[k][tx * 4];
                #pragma unroll
                for (int i = 0; i < 4; ++i)
                    #pragma unroll
                    for (int j = 0; j < 4; ++j) acc[i][j] += av[i] * bv[j];
            }
            __syncthreads();
        }
    }
    float p[4] = {0.f, 0.f, 0.f, 0.f};
    #pragma unroll
    for (int i = 0; i < 4; ++i) {
        const float wv = whq[m0 + ty * 4 + i];
        #pragma unroll
        for (int j = 0; j < 4; ++j) p[j] += wv * fast_tanh(acc3[i][j] + acc[i][j]);
    }
    #pragma unroll
    for (int j = 0; j < 4; ++j) red[ty][tx * 4 + j] = p[j];
    __syncthreads();
    if (f < BN) {
        float s = 0.f;
        #pragma unroll
        for (int r = 0; r < 16; ++r) s += red[r][f];
        atomicAdd(&logits[(size_t)b * N + n0 + f], s);
    }
}

// ---------------------------------------------------------------------------
extern "C" void kernel_launch(void* const* d_in, const int* in_sizes, int n_in,
                              void* d_out, int out_size, void* d_ws, size_t ws_size,
                              hipStream_t stream) {
    const float* z_robot = (const float*)d_in[0];
    const float* z_human = (const float*)d_in[1];
    const float* W_b     = (const float*)d_in[2];
    const float* W_q     = (const float*)d_in[3];
    const float* W_v     = (const float*)d_in[4];
    const float* w_hq    = (const float*)d_in[5];
    float* out = (float*)d_out;

    const int Bn = 32, S = 512, T = 1024;
    float* attn_out = out;
    float* aq_out   = out + (size_t)Bn * S;
    float* C_out    = out + (size_t)Bn * S + (size_t)Bn * T;

    char* ws = (char*)d_ws;
    const size_t E2 = 33554432;  // bytes of one bf16 [32][1024][512] buffer

    ushort* zhT_hi  = (ushort*)(ws);
    ushort* zhT_lo  = (ushort*)(ws + E2);
    ushort* zrT_hi  = (ushort*)(ws + 2 * E2);
    ushort* zrT_lo  = (ushort*)(ws + 3 * E2);
    ushort* auxT_hi = (ushort*)(ws + 4 * E2);
    ushort* auxT_lo = (ushort*)(ws + 5 * E2);
    ushort* C16     = (ushort*)(ws + 6 * E2);   // 2*E2 bytes
    ushort* aux2    = auxT_hi;                  // alias: auxT dead after G2
    ushort* Wb_hi   = (ushort*)(ws + 8 * E2);
    ushort* Wb_lo   = Wb_hi + 262144;
    ushort* Wq16    = Wb_hi + 524288;
    ushort* Wv16    = Wb_hi + 786432;
    float*  logitsF = (float*)(ws + 8 * E2 + 2097152);
    const size_t FAST_REQ = 8 * E2 + 2097152 + 131072;

    if (ws_size >= FAST_REQ) {
        hipMemsetAsync(logitsF, 0, (size_t)Bn * T * sizeof(float), stream);
        transpose_split2_k<<<dim3(32, 8, 64), dim3(32, 8), 0, stream>>>(
            z_human, zhT_hi, zhT_lo, z_robot, zrT_hi, zrT_lo);
        convert_weights_k<<<dim3(3072), dim3(256), 0, stream>>>(
            W_b, W_q, W_v, Wb_hi, Wb_lo, Wq16, Wv16);
        // G1: auxT[b][h][s]; 32 tiles/batch (8m x 4n)
        gemm_split<0><<<dim3(32 * 32), dim3(256), 0, stream>>>(
            zhT_hi, zhT_lo, 524288, 512, Wb_hi, Wb_lo, 0, 512, 512,
            auxT_hi, auxT_lo, nullptr, nullptr, 512, 524288, 32, 4);
        // G2: C[b][t][h] = tanh(zrT @ auxT^T); 64 tiles/batch (8m x 8n)
        gemm_split<1><<<dim3(32 * 64), dim3(256), 0, stream>>>(
            zrT_hi, zrT_lo, 524288, 512, auxT_hi, auxT_lo, 524288, 512, 512,
            nullptr, nullptr, C_out, C16, 1024, 1048576, 64, 8);
        // G3: aux2[b][f][h]; 32 tiles/batch (4m x 8n)
        gemm_plain_store<<<dim3(32 * 32), dim3(256), 0, stream>>>(
            Wv16, 0, 512, zhT_hi, 524288, 512, 512, aux2, 524288, 1024, 32, 8);
        // G4: logits; 32 tiles/batch (4m x 8n)
        gemm_fused_logits<<<dim3(32 * 32), dim3(256), 0, stream>>>(
            Wq16, zrT_hi, aux2, C16, w_hq, logitsF, 32, 8);
        softmax_kernel<<<dim3(Bn), dim3(256), 0, stream>>>(logitsF, aq_out, T);
        attn_kernel<<<dim3(S / 4, Bn), dim3(256), 0, stream>>>(z_robot, aq_out, attn_out, S, T);
    } else {
        float* ws0    = (float*)ws;
        float* logits = (float*)(ws + (size_t)Bn * S * T * 4);
        hipMemsetAsync(logits, 0, (size_t)Bn * T * sizeof(float), stream);
        dim3 blk(16, 16);
        gemm_nn<<<dim3(T / BN, S / BM, Bn), blk, 0, stream>>>(W_b, z_human, ws0, S, T, S);
        gemm_tn_tanh<<<dim3(T / BN, T / BM, Bn), blk, 0, stream>>>(z_robot, ws0, C_out, T, T, S);
        gemm_nn<<<dim3(T / BN, 512 / BM, Bn), blk, 0, stream>>>(W_v, z_human, ws0, 512, T, S);
        gemm_nt_fused<<<dim3(T / BN, 512 / BM, Bn), blk, 0, stream>>>(
            W_q, z_robot, ws0, C_out, w_hq, logits, 512, T, S, T);
        softmax_kernel<<<dim3(Bn), dim3(256), 0, stream>>>(logits, aq_out, T);
        attn_kernel<<<dim3(S / 4, Bn), dim3(256), 0, stream>>>(z_robot, aq_out, attn_out, S, T);
    }
}